// Round 11
// baseline (513.549 us; speedup 1.0000x reference)
//
#include <hip/hip_runtime.h>
#include <hip/hip_bf16.h>

#define D_MODEL 1024
#define N_HEADS 16
#define D_HEAD  64
#define D_FF    4096
#define BATCH   4
#define SEQ     2048
#define ROWS    (BATCH*SEQ)   // 8192
#define LN_EPS  1e-5f

typedef __bf16 bf16;
typedef __bf16 bf16x8 __attribute__((ext_vector_type(8)));
typedef __bf16 bf16x4 __attribute__((ext_vector_type(4)));
typedef float  f32x4  __attribute__((ext_vector_type(4)));

// ---- async global->LDS 16B copy: dst is WAVE-UNIFORM base, HW adds lane*16B ----
__device__ __forceinline__ void load16_lds(const bf16* g, bf16* l) {
#if defined(__has_builtin) && __has_builtin(__builtin_amdgcn_global_load_lds)
    __builtin_amdgcn_global_load_lds(
        (const __attribute__((address_space(1))) unsigned int*)g,
        (__attribute__((address_space(3))) unsigned int*)l,
        16, 0, 0);
#else
    const int lane = threadIdx.x & 63;
    ((bf16x8*)l)[lane] = *(const bf16x8*)g;
#endif
}

// ---------------- fp32 -> bf16 converts (batched) ----------------
__global__ __launch_bounds__(256) void f2b4_kernel(const float* a, const float* b,
                                                   const float* c, const float* d,
                                                   bf16* oa, bf16* ob, bf16* oc, bf16* od,
                                                   int n) {
    const float* srcs[4] = {a, b, c, d};
    bf16* dsts[4] = {oa, ob, oc, od};
    const float* s = srcs[blockIdx.y];
    bf16* dst = dsts[blockIdx.y];
    int i = blockIdx.x * 256 + threadIdx.x;
    int stride = gridDim.x * 256;
    for (; i < n; i += stride) dst[i] = (bf16)s[i];
}
__global__ __launch_bounds__(256) void f2b2_kernel(const float* a, const float* b,
                                                   bf16* oa, bf16* ob, int n) {
    const float* s = blockIdx.y ? b : a;
    bf16* dst = blockIdx.y ? ob : oa;
    int i = blockIdx.x * 256 + threadIdx.x;
    int stride = gridDim.x * 256;
    for (; i < n; i += stride) dst[i] = (bf16)s[i];
}

// ---------------- LayerNorm: fp32 in -> bf16 out, one block per row ----------------
__global__ __launch_bounds__(256) void ln_kernel(const float* __restrict__ x,
                                                 const float* __restrict__ gamma,
                                                 const float* __restrict__ beta,
                                                 bf16* __restrict__ out) {
    const int row = blockIdx.x;
    const int tid = threadIdx.x;
    const float* xr = x + (size_t)row * D_MODEL;

    float vals[4];
    float s = 0.f, ss = 0.f;
#pragma unroll
    for (int t = 0; t < 4; ++t) {
        float v = xr[tid + t * 256];
        vals[t] = v;
        s += v;
        ss += v * v;
    }
#pragma unroll
    for (int off = 32; off > 0; off >>= 1) {
        s  += __shfl_xor(s, off, 64);
        ss += __shfl_xor(ss, off, 64);
    }
    __shared__ float sbuf[4], ssbuf[4];
    const int wave = tid >> 6;
    if ((tid & 63) == 0) { sbuf[wave] = s; ssbuf[wave] = ss; }
    __syncthreads();
    s  = sbuf[0] + sbuf[1] + sbuf[2] + sbuf[3];
    ss = ssbuf[0] + ssbuf[1] + ssbuf[2] + ssbuf[3];

    const float mean = s * (1.f / D_MODEL);
    const float var  = ss * (1.f / D_MODEL) - mean * mean;
    const float inv  = rsqrtf(var + LN_EPS);

    bf16* orow = out + (size_t)row * D_MODEL;
#pragma unroll
    for (int t = 0; t < 4; ++t) {
        int c = tid + t * 256;
        orow[c] = (bf16)(gamma[c] * ((vals[t] - mean) * inv) + beta[c]);
    }
}

// ---------------- GELU: 0.5x(1+tanh(y)) == x/(1+exp(-2y)), hardware v_exp_f32 ----------------
__device__ __forceinline__ float gelu_f(float x) {
    const float y = x * (0.7978845608f + 0.0356774081f * x * x);  // 0.7978845608*(x+0.044715x^3)
    return x / (1.f + __expf(-2.f * y));
}

// ---------------- GEMM m97-style, XCD-affine swizzle ----------------
// 1D grid.x of (N/TN)*(M/128) blocks. Block id b: xcd = b&7 (HW round-robin), j = b>>3.
// ORD=0 (band-outer): bx = j%nN, band = (j/nN)*8+xcd.
// ORD=1 (N-outer): bx = j/BPX, band = (j%BPX)*8+xcd; BPX=(M/128)/8.
// CONFIG IS FROZEN as the R7 bundle (e2e 512.7 -> R10 499.5): QKV ORD1,
// FC1 TN=128/ORD1, WO/FC2 TN=64/ORD0. R8/R9: per-dispatch times are NOT additive
// (L3-residency coupling); judge GEMM configs by e2e only; do not unbundle.
// BK=64: rows are 128B -> XOR chunk-swizzle (G4): global source pre-swizzled
//   (lane&7)^lrow so LDS dest stays linear (rule 21); read slot = chunk^(row&7).
//   (R3: FC2 conflict counter 8.4M->~0; R4: FC1/QKV. SQ_LDS_BANK_CONFLICT = 0.)
// R11: PP ping-pong double-buffer for EPI!=4 (flash-proven): stage tile k+1 into
//   the other buffer BEFORE computing tile k; ONE barrier per K-step (its vmcnt
//   drain lands the prefetch). Staging latency hides under ds_read+MFMA instead
//   of being exposed at a dedicated barrier. LDS 2x: FC1 64KB (2 blk/CU),
//   WO/FC2 48KB (3 blk/CU) — intra-block overlap replaces cross-block.
// EPI: 0 plain; 1 gelu; 2 v += ADD[idx] fp32 (C may alias ADD);
//      4 fused-QKV: cols [0,2048) -> C row stride 2048 (q pre-scaled 1/8 | k),
//        cols [2048,3072) -> VT transposed [B,H,dh,S] via per-wave LDS (TN=128 only).
//        tbuf ALIASES sA/sB (union): only used after the K-loop's final barrier.
template <int EPI, int TN, int BK, int ORD, typename OutT>
__global__ __launch_bounds__(256) void gemm_mt(const bf16* __restrict__ A,
                                               const bf16* __restrict__ W,
                                               OutT* C,
                                               const float* ADD,
                                               bf16* VT,
                                               int M, int N, int K, int LDK) {
    constexpr int WN = TN / 64;          // waves along N
    constexpr int WM = 4 / WN;           // waves along M
    constexpr int SM = (128 / WM) / 16;  // M-subtiles per wave

    constexpr bool PP = (EPI != 4) && (BK == 64);   // ping-pong double-buffer
    constexpr int BUFE = 128 * BK + TN * BK;        // elems per buffer (A then B)
    constexpr int AB_ELEMS = (PP ? 2 : 1) * BUFE;
    constexpr int TB_ELEMS = (EPI == 4) ? 4 * 64 * 72 : 0;
    constexpr int SMEM_ELEMS = AB_ELEMS > TB_ELEMS ? AB_ELEMS : TB_ELEMS;
    __shared__ __align__(16) bf16 smem[SMEM_ELEMS];
    bf16* sA   = smem;
    bf16* sB   = smem + 128 * BK;
    bf16* tbuf = smem;                   // EPI==4 epilogue only (sA/sB dead by then)

    const int wave = threadIdx.x >> 6;
    const int lane = threadIdx.x & 63;
    const int quad = lane >> 4;
    const int l16  = lane & 15;
    const int wm   = wave / WN;
    const int wn   = wave % WN;

    // XCD-affine decode
    const int nN  = N / TN;
    const int b   = blockIdx.x;
    const int xcd = b & 7;
    const int j   = b >> 3;
    int bx, band;
    if constexpr (ORD == 0) {
        bx   = j % nN;
        band = (j / nN) * 8 + xcd;
    } else {
        const int BPX = (M / 128) >> 3;  // bands per XCD
        bx   = j / BPX;
        band = (j % BPX) * 8 + xcd;
    }

    const int m0 = band * 128;
    const int n0 = bx * TN;

    f32x4 acc[SM][4] = {};

    if constexpr (BK == 32) {
        const int srow = lane >> 2;          // 0..15
        const int scol = (lane & 3) * 8;
        const bf16* gA0 = A + (size_t)(m0 + wave * 32 + srow) * LDK + scol;
        const bf16* gA1 = gA0 + (size_t)16 * LDK;
        bf16* lA0 = &sA[(wave * 32) * 32];
        bf16* lA1 = &sA[(wave * 32 + 16) * 32];
        const bf16* gB0 = W + (size_t)(n0 + wave * (TN / 4) + srow) * LDK + scol;
        const bf16* gB1 = gB0 + (size_t)16 * LDK;
        bf16* lB0 = &sB[(wave * (TN / 4)) * 32];
        bf16* lB1 = &sB[(wave * (TN / 4) + 16) * 32];

        for (int k0 = 0; k0 < K; k0 += 32) {
            load16_lds(gA0 + k0, lA0);
            load16_lds(gA1 + k0, lA1);
            load16_lds(gB0 + k0, lB0);
            if constexpr (TN == 128) load16_lds(gB1 + k0, lB1);
            __syncthreads();

            bf16x8 af[SM], bfr[4];
#pragma unroll
            for (int s = 0; s < SM; ++s)
                af[s] = *reinterpret_cast<const bf16x8*>(&sA[(wm * (128 / WM) + s * 16 + l16) * 32 + quad * 8]);
#pragma unroll
            for (int t = 0; t < 4; ++t)
                bfr[t] = *reinterpret_cast<const bf16x8*>(&sB[(wn * 64 + t * 16 + l16) * 32 + quad * 8]);
#pragma unroll
            for (int s = 0; s < SM; ++s)
#pragma unroll
                for (int t = 0; t < 4; ++t)
                    acc[s][t] = __builtin_amdgcn_mfma_f32_16x16x32_bf16(af[s], bfr[t], acc[s][t], 0, 0, 0);
            __syncthreads();
        }
    } else {
        // BK == 64: swizzled staging. Each 1KB load covers 8 rows x 64 cols.
        const int lrow = lane >> 3;                    // 0..7
        const int lch  = ((lane & 7) ^ lrow) * 8;      // pre-swizzled global col chunk
        const bf16* gA = A + (size_t)(m0 + wave * 32 + lrow) * LDK + lch;
        const bf16* gB = W + (size_t)(n0 + wave * (TN / 4) + lrow) * LDK + lch;

        auto stageg = [&](int k0, int buf) {
            bf16* lA = smem + buf * BUFE + (wave * 32) * 64;
            bf16* lB = smem + buf * BUFE + 128 * BK + (wave * (TN / 4)) * 64;
#pragma unroll
            for (int i = 0; i < 4; ++i)
                load16_lds(gA + k0 + (size_t)(8 * i) * LDK, lA + 8 * i * 64);
#pragma unroll
            for (int i = 0; i < (TN / 4) / 8; ++i)
                load16_lds(gB + k0 + (size_t)(8 * i) * LDK, lB + 8 * i * 64);
        };
        auto comp = [&](int buf) {
            const bf16* cA = smem + buf * BUFE;
            const bf16* cB = cA + 128 * BK;
#pragma unroll
            for (int kk = 0; kk < 2; ++kk) {
                bf16x8 af[SM], bfr[4];
#pragma unroll
                for (int s = 0; s < SM; ++s) {
                    const int row = wm * (128 / WM) + s * 16 + l16;
                    const int sl  = (kk * 4 + quad) ^ (row & 7);
                    af[s] = *reinterpret_cast<const bf16x8*>(&cA[row * 64 + sl * 8]);
                }
#pragma unroll
                for (int t = 0; t < 4; ++t) {
                    const int row = wn * 64 + t * 16 + l16;
                    const int sl  = (kk * 4 + quad) ^ (row & 7);
                    bfr[t] = *reinterpret_cast<const bf16x8*>(&cB[row * 64 + sl * 8]);
                }
#pragma unroll
                for (int s = 0; s < SM; ++s)
#pragma unroll
                    for (int t = 0; t < 4; ++t)
                        acc[s][t] = __builtin_amdgcn_mfma_f32_16x16x32_bf16(af[s], bfr[t], acc[s][t], 0, 0, 0);
            }
        };

        if constexpr (PP) {
            // R11 ping-pong: one barrier per K-step; prefetch of k+1 lands at the
            // same barrier that releases the reads of buffer cur (vmcnt drain).
            stageg(0, 0);
            __syncthreads();
            int cur = 0;
            for (int k0 = 0; k0 < K; k0 += 64) {
                if (k0 + 64 < K) stageg(k0 + 64, cur ^ 1);
                comp(cur);
                __syncthreads();
                cur ^= 1;
            }
        } else {
            for (int k0 = 0; k0 < K; k0 += 64) {
                stageg(k0, 0);
                __syncthreads();
                comp(0);
                __syncthreads();
            }
        }
    }

    if constexpr (EPI == 4) {
        if (n0 >= 2048) {
            // V columns: per-wave transpose through LDS (64x64, stride 72), store [B,H,dh,S]
            bf16* tw = &tbuf[wave * 64 * 72];
#pragma unroll
            for (int s = 0; s < SM; ++s)
#pragma unroll
                for (int t = 0; t < 4; ++t)
#pragma unroll
                    for (int r = 0; r < 4; ++r)
                        tw[(t * 16 + l16) * 72 + s * 16 + quad * 4 + r] = (bf16)acc[s][t][r];
#pragma unroll
            for (int i = 0; i < 8; ++i) {
                const int flat = i * 64 + lane;
                const int nl = flat >> 3;
                const int mc = flat & 7;
                bf16x8 v = *reinterpret_cast<const bf16x8*>(&tw[nl * 72 + mc * 8]);
                const int vcol = n0 - 2048 + wn * 64 + nl;
                const int m_glob = m0 + wm * 64 + mc * 8;
                const int bb = m_glob >> 11, sp = m_glob & (SEQ - 1);
                const int hh = vcol >> 6,  dh = vcol & 63;
                const size_t tidx = (((size_t)(bb * N_HEADS + hh) * D_HEAD + dh) << 11) + sp;
                *reinterpret_cast<bf16x8*>(&VT[tidx]) = v;
            }
        } else {
            // Q|K columns: row stride 2048; Q pre-scaled by 1/sqrt(dh)
            const float qscale = (n0 < 1024) ? 0.125f : 1.0f;
#pragma unroll
            for (int s = 0; s < SM; ++s) {
                const int mbase = m0 + wm * (128 / WM) + s * 16 + quad * 4;
#pragma unroll
                for (int t = 0; t < 4; ++t) {
                    const int n = n0 + wn * 64 + t * 16 + l16;
#pragma unroll
                    for (int r = 0; r < 4; ++r)
                        C[(size_t)(mbase + r) * 2048 + n] = (OutT)(acc[s][t][r] * qscale);
                }
            }
        }
    } else {
#pragma unroll
        for (int s = 0; s < SM; ++s) {
            const int mbase = m0 + wm * (128 / WM) + s * 16 + quad * 4;
#pragma unroll
            for (int t = 0; t < 4; ++t) {
                const int n = n0 + wn * 64 + t * 16 + l16;
#pragma unroll
                for (int r = 0; r < 4; ++r) {
                    float v = acc[s][t][r];
                    if (EPI == 1) v = gelu_f(v);
                    const size_t idx = (size_t)(mbase + r) * N + n;
                    if (EPI == 2) v += ADD[idx];
                    C[idx] = (OutT)v;
                }
            }
        }
    }
}

// ---------------- Flash attention: swapped QK^T + sigma-permuted K staging (R5) ----------------
// R10: + s_setprio(1) around MFMA clusters (T5) and defer-max rescale skip (T13, THR=8).
__global__ __launch_bounds__(256) void flash_attn_kernel(const bf16* __restrict__ qk,
                                                         const bf16* __restrict__ vt,
                                                         bf16* __restrict__ o) {
    const int id   = blockIdx.x;
    const int bhl  = id & 7;
    const int rest = id >> 3;
    const int pair = rest & 15;
    const int bhh  = rest >> 4;
    const int bh   = bhh * 8 + bhl;
    const int b    = bh >> 4;
    const int h    = bh & 15;
    const int wave = threadIdx.x >> 6;
    const int lane = threadIdx.x & 63;
    const int quad = lane >> 4;
    const int l16  = lane & 15;

    __shared__ __align__(16) bf16 sK[2][64 * 64];   // [buf][sigma-permuted key][dh]
    __shared__ __align__(16) bf16 sV[2][64 * 64];   // [buf][dh][key]

    const bf16* kbase = qk + (size_t)(b * SEQ) * 2048 + 1024 + h * D_HEAD;
    const bf16* vbase = vt + ((size_t)(bh * D_HEAD) << 11);   // [dh][S]

    const int lrow   = lane >> 3;              // 0..7
    const int lchunk = (lane & 7) ^ lrow;      // gather-side xor swizzle
    const int xr     = l16 & 7;                // read-side xor

    // sigma: LDS key-row i holds global key j0 + sigma(i)
    auto sig = [](int i) { return (i & 32) + (((i >> 2) & 3) << 3) + (((i >> 4) & 1) << 2) + (i & 3); };
    const int sg0 = sig(wave * 16 + lrow);
    const int sg1 = sig(wave * 16 + 8 + lrow);

    auto stage = [&](int j0, int buf) {
        const bf16* gk0 = kbase + (size_t)(j0 + sg0) * 2048 + lchunk * 8;
        const bf16* gk1 = kbase + (size_t)(j0 + sg1) * 2048 + lchunk * 8;
        const bf16* gv  = vbase + (size_t)(wave * 16 + lrow) * 2048 + j0 + lchunk * 8;
        load16_lds(gk0, &sK[buf][(wave * 16) * 64]);
        load16_lds(gk1, &sK[buf][(wave * 16 + 8) * 64]);
        load16_lds(gv,            &sV[buf][(wave * 16) * 64]);
        load16_lds(gv + 8 * 2048, &sV[buf][(wave * 16 + 8) * 64]);
    };

    for (int half = 0; half < 2; ++half) {
        const int qtile = half ? 31 - pair : pair;
        const int q0 = qtile * 64 + wave * 16;
        const int qg = q0 + l16;                         // this lane's q row
        const size_t qrow = (size_t)(b * SEQ + qg) * 2048 + h * D_HEAD;
        bf16x8 qf0 = *reinterpret_cast<const bf16x8*>(qk + qrow + quad * 8);
        bf16x8 qf1 = *reinterpret_cast<const bf16x8*>(qk + qrow + 32 + quad * 8);

        f32x4 o_acc[4] = {(f32x4)(0.f), (f32x4)(0.f), (f32x4)(0.f), (f32x4)(0.f)};
        float m_q = -1e30f;
        float l_r = 0.f;

        stage(0, 0);
        __syncthreads();

        for (int jt = 0; jt <= qtile; ++jt) {
            const int j0 = jt * 64;
            const int cur = jt & 1;
            if (jt < qtile) stage(j0 + 64, cur ^ 1);   // async prefetch into other buffer

            const bf16* sKc = sK[cur];
            const bf16* sVc = sV[cur];

            // S^T = K . Q^T : C[key-row][q-col=l16]
            f32x4 s_acc[4] = {(f32x4)(0.f), (f32x4)(0.f), (f32x4)(0.f), (f32x4)(0.f)};
            __builtin_amdgcn_s_setprio(1);
#pragma unroll
            for (int nb = 0; nb < 4; ++nb) {
                const int row = nb * 16 + l16;
                const int slot = quad ^ xr;
                bf16x8 kf0 = *reinterpret_cast<const bf16x8*>(&sKc[row * 64 + slot * 8]);
                bf16x8 kf1 = *reinterpret_cast<const bf16x8*>(&sKc[row * 64 + (slot ^ 4) * 8]);
                s_acc[nb] = __builtin_amdgcn_mfma_f32_16x16x32_bf16(kf0, qf0, s_acc[nb], 0, 0, 0);
                s_acc[nb] = __builtin_amdgcn_mfma_f32_16x16x32_bf16(kf1, qf1, s_acc[nb], 0, 0, 0);
            }
            __builtin_amdgcn_s_setprio(0);

            const bool diag = (jt == qtile);
            float p[4][4];
            float mx = -1e30f;
#pragma unroll
            for (int nb = 0; nb < 4; ++nb) {
#pragma unroll
                for (int r = 0; r < 4; ++r) {
                    float s = s_acc[nb][r];
                    if (diag) {
                        const int key = j0 + ((nb & 2) << 4) + (quad << 3) + ((nb & 1) << 2) + r;
                        if (key > qg) s = -1e30f;
                    }
                    p[nb][r] = s;
                    mx = fmaxf(mx, s);
                }
            }
            mx = fmaxf(mx, __shfl_xor(mx, 16, 64));
            mx = fmaxf(mx, __shfl_xor(mx, 32, 64));

            // T13 defer-max: only rescale when some q-row's max grew by > 8
            if (!__all(mx <= m_q + 8.0f)) {
                const float mn = fmaxf(m_q, mx);
                const float alpha = __expf(m_q - mn);
                m_q = mn;
                l_r *= alpha;
#pragma unroll
                for (int nb = 0; nb < 4; ++nb) o_acc[nb] *= alpha;
            }

            float ts = 0.f;
#pragma unroll
            for (int nb = 0; nb < 4; ++nb)
#pragma unroll
                for (int r = 0; r < 4; ++r) {
                    const float e = __expf(p[nb][r] - m_q);
                    p[nb][r] = e;
                    ts += e;
                }
            ts += __shfl_xor(ts, 16, 64);
            ts += __shfl_xor(ts, 32, 64);
            l_r += ts;

            bf16x8 pb0, pb1;
#pragma unroll
            for (int r = 0; r < 4; ++r) {
                pb0[r]     = (bf16)p[0][r];
                pb0[4 + r] = (bf16)p[1][r];
                pb1[r]     = (bf16)p[2][r];
                pb1[4 + r] = (bf16)p[3][r];
            }

            // O^T += V^T . P^T : A = V^T fragment, B = pb in regs
            __builtin_amdgcn_s_setprio(1);
#pragma unroll
            for (int nb = 0; nb < 4; ++nb) {
                const int row = nb * 16 + l16;
                const int slot = quad ^ xr;
                bf16x8 vf0 = *reinterpret_cast<const bf16x8*>(&sVc[row * 64 + slot * 8]);
                bf16x8 vf1 = *reinterpret_cast<const bf16x8*>(&sVc[row * 64 + (slot ^ 4) * 8]);
                o_acc[nb] = __builtin_amdgcn_mfma_f32_16x16x32_bf16(vf0, pb0, o_acc[nb], 0, 0, 0);
                o_acc[nb] = __builtin_amdgcn_mfma_f32_16x16x32_bf16(vf1, pb1, o_acc[nb], 0, 0, 0);
            }
            __builtin_amdgcn_s_setprio(0);
            __syncthreads();   // all waves done with cur; prefetch landed (vmcnt drain)
        }

        const float inv = 1.f / l_r;
#pragma unroll
        for (int nb = 0; nb < 4; ++nb) {
            bf16x4 ov;
#pragma unroll
            for (int r = 0; r < 4; ++r) ov[r] = (bf16)(o_acc[nb][r] * inv);
            *reinterpret_cast<bf16x4*>(
                &o[(size_t)(b * SEQ + qg) * D_MODEL + h * D_HEAD + nb * 16 + quad * 4]) = ov;
        }
    }
}

// ---------------- launch ----------------
// fp32 I/O. resid lives in d_out. Workspace (lifetime-aliased):
//   [0,24)   MB : bf16 weights wq|wk|wv (=wqkv) |wo|fc1|fc2
//   [24,40)  MB : n1 -> attn -> hid(start)
//   [40,72)  MB : qk [8192,2048] (dead after flash)
//   [72,88)  MB : vT (dead after flash)
//   MLP: if ws >= 104 MB: hid = [24,88), n2 = [88,104); else 2-chunk, n2 = [72,88).
extern "C" void kernel_launch(void* const* d_in, const int* in_sizes, int n_in,
                              void* d_out, int out_size, void* d_ws, size_t ws_size,
                              hipStream_t stream) {
    const float* x      = (const float*)d_in[0];
    const float* gamma1 = (const float*)d_in[1];
    const float* beta1  = (const float*)d_in[2];
    const float* wq     = (const float*)d_in[3];
    const float* wk     = (const float*)d_in[4];
    const float* wv     = (const float*)d_in[5];
    const float* wo     = (const float*)d_in[6];
    const float* gamma2 = (const float*)d_in[7];
    const float* beta2  = (const float*)d_in[8];
    const float* fc1    = (const float*)d_in[9];
    const float* fc2    = (const float*)d_in[10];
    float* out = (float*)d_out;

    const size_t WSMALL = (size_t)N_HEADS * D_HEAD * D_MODEL;  // 1,048,576
    const size_t WFF    = (size_t)D_FF * D_MODEL;              // 4,194,304
    const size_t RD     = (size_t)ROWS * D_MODEL;              // 8,388,608

    char* wsb = (char*)d_ws;
    bf16* wq_b  = (bf16*)(wsb);           // wq|wk|wv contiguous = wqkv [3072,1024]
    bf16* wk_b  = wq_b + WSMALL;
    bf16* wv_b  = wk_b + WSMALL;
    bf16* wo_b  = wv_b + WSMALL;
    bf16* fc1_b = wo_b + WSMALL;
    bf16* fc2_b = fc1_b + WFF;            // ends at 24 MB
    bf16* slotA = fc2_b + WFF;            // [24,40): n1 -> attn -> hid
    bf16* qkb   = slotA + RD;             // [40,72): q|k stride-2048
    bf16* vtb   = qkb + 2 * RD;           // [72,88)

    bf16* n1    = slotA;
    bf16* attnb = slotA;
    bf16* hid   = slotA;
    float* resid = out;

    const size_t need_single = (size_t)(24 + 64 + 16) * 1024 * 1024;
    const bool single = ws_size >= need_single;
    bf16* n2 = single ? (bf16*)(wsb + (size_t)88 * 1024 * 1024) : vtb;

    // weight conversion fp32 -> bf16
    f2b4_kernel<<<dim3(64, 4), 256, 0, stream>>>(wq, wk, wv, wo, wq_b, wk_b, wv_b, wo_b, (int)WSMALL);
    f2b2_kernel<<<dim3(256, 2), 256, 0, stream>>>(fc1, fc2, fc1_b, fc2_b, (int)WFF);

    // LN1
    ln_kernel<<<ROWS, 256, 0, stream>>>(x, gamma1, beta1, n1);
    // fused QKV: BK=64 swizzled + tbuf union (R4); ORD=1 (R7 frozen bundle)
    gemm_mt<4, 128, 64, 1, bf16><<<(3072 / 128) * (ROWS / 128), 256, 0, stream>>>(n1, wq_b, qkb, nullptr, vtb, ROWS, 3072, D_MODEL, D_MODEL);
    // flash attention (R5 structure + R10 setprio/defer-max)
    flash_attn_kernel<<<1024, 256, 0, stream>>>(qkb, vtb, attnb);
    // resid(d_out) = x + attn @ wo^T — TN=64/ORD=0 + R11 ping-pong
    gemm_mt<2, 64, 64, 0, float><<<(D_MODEL / 64) * (ROWS / 128), 256, 0, stream>>>(attnb, wo_b, resid, x, nullptr, ROWS, D_MODEL, D_MODEL, D_MODEL);
    // LN2
    ln_kernel<<<ROWS, 256, 0, stream>>>(resid, gamma2, beta2, n2);

    if (single) {
        // FC1: TN=128/BK=64/ORD=1 (frozen) + R11 ping-pong (LDS 64KB, 2 blk/CU)
        gemm_mt<1, 128, 64, 1, bf16><<<(D_FF / 128) * (ROWS / 128), 256, 0, stream>>>(n2, fc1_b, hid, nullptr, nullptr, ROWS, D_FF, D_MODEL, D_MODEL);
        // FC2: TN=64/ORD=0 + R11 ping-pong (LDS 48KB, 3 blk/CU)
        gemm_mt<2, 64, 64, 0, float><<<(D_MODEL / 64) * (ROWS / 128), 256, 0, stream>>>(hid, fc2_b, out, resid, nullptr, ROWS, D_MODEL, D_FF, D_FF);
    } else {
        const int CHUNK = 4096;   // hid chunk = 32 MB in [24,56); CHUNK/128 = 32 (div by 8 ok)
        for (int c = 0; c < ROWS / CHUNK; ++c) {
            const bf16*  n2c    = n2    + (size_t)c * CHUNK * D_MODEL;
            const float* residc = resid + (size_t)c * CHUNK * D_MODEL;
            float*       outc   = out   + (size_t)c * CHUNK * D_MODEL;
            gemm_mt<1, 128, 64, 1, bf16><<<(D_FF / 128) * (CHUNK / 128), 256, 0, stream>>>(n2c, fc1_b, hid, nullptr, nullptr, CHUNK, D_FF, D_MODEL, D_MODEL);
            gemm_mt<2, 64, 64, 0, float><<<(D_MODEL / 64) * (CHUNK / 128), 256, 0, stream>>>(hid, fc2_b, outc, residc, nullptr, CHUNK, D_MODEL, D_FF, D_FF);
        }
    }
}

// Round 12
// 500.634 us; speedup vs baseline: 1.0258x; 1.0258x over previous
//
#include <hip/hip_runtime.h>
#include <hip/hip_bf16.h>

#define D_MODEL 1024
#define N_HEADS 16
#define D_HEAD  64
#define D_FF    4096
#define BATCH   4
#define SEQ     2048
#define ROWS    (BATCH*SEQ)   // 8192
#define LN_EPS  1e-5f

typedef __bf16 bf16;
typedef __bf16 bf16x8 __attribute__((ext_vector_type(8)));
typedef __bf16 bf16x4 __attribute__((ext_vector_type(4)));
typedef float  f32x4  __attribute__((ext_vector_type(4)));

// ---- async global->LDS 16B copy: dst is WAVE-UNIFORM base, HW adds lane*16B ----
__device__ __forceinline__ void load16_lds(const bf16* g, bf16* l) {
#if defined(__has_builtin) && __has_builtin(__builtin_amdgcn_global_load_lds)
    __builtin_amdgcn_global_load_lds(
        (const __attribute__((address_space(1))) unsigned int*)g,
        (__attribute__((address_space(3))) unsigned int*)l,
        16, 0, 0);
#else
    const int lane = threadIdx.x & 63;
    ((bf16x8*)l)[lane] = *(const bf16x8*)g;
#endif
}

// ---------------- fp32 -> bf16 converts (batched) ----------------
__global__ __launch_bounds__(256) void f2b4_kernel(const float* a, const float* b,
                                                   const float* c, const float* d,
                                                   bf16* oa, bf16* ob, bf16* oc, bf16* od,
                                                   int n) {
    const float* srcs[4] = {a, b, c, d};
    bf16* dsts[4] = {oa, ob, oc, od};
    const float* s = srcs[blockIdx.y];
    bf16* dst = dsts[blockIdx.y];
    int i = blockIdx.x * 256 + threadIdx.x;
    int stride = gridDim.x * 256;
    for (; i < n; i += stride) dst[i] = (bf16)s[i];
}
__global__ __launch_bounds__(256) void f2b2_kernel(const float* a, const float* b,
                                                   bf16* oa, bf16* ob, int n) {
    const float* s = blockIdx.y ? b : a;
    bf16* dst = blockIdx.y ? ob : oa;
    int i = blockIdx.x * 256 + threadIdx.x;
    int stride = gridDim.x * 256;
    for (; i < n; i += stride) dst[i] = (bf16)s[i];
}

// ---------------- LayerNorm: fp32 in -> bf16 out, one block per row ----------------
__global__ __launch_bounds__(256) void ln_kernel(const float* __restrict__ x,
                                                 const float* __restrict__ gamma,
                                                 const float* __restrict__ beta,
                                                 bf16* __restrict__ out) {
    const int row = blockIdx.x;
    const int tid = threadIdx.x;
    const float* xr = x + (size_t)row * D_MODEL;

    float vals[4];
    float s = 0.f, ss = 0.f;
#pragma unroll
    for (int t = 0; t < 4; ++t) {
        float v = xr[tid + t * 256];
        vals[t] = v;
        s += v;
        ss += v * v;
    }
#pragma unroll
    for (int off = 32; off > 0; off >>= 1) {
        s  += __shfl_xor(s, off, 64);
        ss += __shfl_xor(ss, off, 64);
    }
    __shared__ float sbuf[4], ssbuf[4];
    const int wave = tid >> 6;
    if ((tid & 63) == 0) { sbuf[wave] = s; ssbuf[wave] = ss; }
    __syncthreads();
    s  = sbuf[0] + sbuf[1] + sbuf[2] + sbuf[3];
    ss = ssbuf[0] + ssbuf[1] + ssbuf[2] + ssbuf[3];

    const float mean = s * (1.f / D_MODEL);
    const float var  = ss * (1.f / D_MODEL) - mean * mean;
    const float inv  = rsqrtf(var + LN_EPS);

    bf16* orow = out + (size_t)row * D_MODEL;
#pragma unroll
    for (int t = 0; t < 4; ++t) {
        int c = tid + t * 256;
        orow[c] = (bf16)(gamma[c] * ((vals[t] - mean) * inv) + beta[c]);
    }
}

// ---------------- GELU: 0.5x(1+tanh(y)) == x/(1+exp(-2y)), hardware v_exp_f32 ----------------
__device__ __forceinline__ float gelu_f(float x) {
    const float y = x * (0.7978845608f + 0.0356774081f * x * x);  // 0.7978845608*(x+0.044715x^3)
    return x / (1.f + __expf(-2.f * y));
}

// ---------------- GEMM m97-style, XCD-affine swizzle ----------------
// 1D grid.x of (N/TN)*(M/128) blocks. Block id b: xcd = b&7 (HW round-robin), j = b>>3.
// ORD=0 (band-outer): bx = j%nN, band = (j/nN)*8+xcd.
// ORD=1 (N-outer): bx = j/BPX, band = (j%BPX)*8+xcd; BPX=(M/128)/8.
// CONFIG FROZEN as the R7 bundle (R10 e2e 499.5): QKV ORD1, FC1 TN=128/ORD1,
// WO/FC2 TN=64/ORD0. R8/R9: per-dispatch times are NOT additive (L3 coupling).
// BK=64: rows are 128B -> XOR chunk-swizzle (G4): global source pre-swizzled
//   (lane&7)^lrow so LDS dest stays linear (rule 21); read slot = chunk^(row&7).
//   SQ_LDS_BANK_CONFLICT = 0 since R3/R4.
// R11 LESSON (drain0-PP regressed FC2 90->112, VALUBusy 52->20): __syncthreads'
//   implicit vmcnt(0) drains the just-issued prefetch; with only ~16 MFMA between
//   issue and drain the full load latency is exposed AND occupancy halved.
// R12: counted-vmcnt ping-pong (T4): wait vmcnt(NL) = only the buffer about to be
//   read; the other buffer's NL loads stay in flight ACROSS both raw s_barriers.
//   Wait targets loads issued 2 K-steps ago. Own-vmcnt-then-barrier ordering
//   (m194-m199 pattern); ds_reads drained by lgkmcnt data-dep before barrier 2;
//   sched_barrier(0) pins reordering (rule 18). Last iter: vmcnt(0).
// EPI: 0 plain; 1 gelu; 2 v += ADD[idx] fp32 (C may alias ADD);
//      4 fused-QKV: cols [0,2048) -> C row stride 2048 (q pre-scaled 1/8 | k),
//        cols [2048,3072) -> VT transposed [B,H,dh,S] via per-wave LDS (TN=128 only).
//        tbuf ALIASES sA/sB (union): only used after the K-loop's final barrier.
template <int EPI, int TN, int BK, int ORD, typename OutT>
__global__ __launch_bounds__(256) void gemm_mt(const bf16* __restrict__ A,
                                               const bf16* __restrict__ W,
                                               OutT* C,
                                               const float* ADD,
                                               bf16* VT,
                                               int M, int N, int K, int LDK) {
    constexpr int WN = TN / 64;          // waves along N
    constexpr int WM = 4 / WN;           // waves along M
    constexpr int SM = (128 / WM) / 16;  // M-subtiles per wave

    constexpr bool PP = (EPI != 4) && (BK == 64);   // counted-vmcnt ping-pong
    constexpr int BUFE = 128 * BK + TN * BK;        // elems per buffer (A then B)
    constexpr int AB_ELEMS = (PP ? 2 : 1) * BUFE;
    constexpr int TB_ELEMS = (EPI == 4) ? 4 * 64 * 72 : 0;
    constexpr int SMEM_ELEMS = AB_ELEMS > TB_ELEMS ? AB_ELEMS : TB_ELEMS;
    __shared__ __align__(16) bf16 smem[SMEM_ELEMS];
    bf16* sA   = smem;
    bf16* sB   = smem + 128 * BK;
    bf16* tbuf = smem;                   // EPI==4 epilogue only (sA/sB dead by then)

    const int wave = threadIdx.x >> 6;
    const int lane = threadIdx.x & 63;
    const int quad = lane >> 4;
    const int l16  = lane & 15;
    const int wm   = wave / WN;
    const int wn   = wave % WN;

    // XCD-affine decode
    const int nN  = N / TN;
    const int b   = blockIdx.x;
    const int xcd = b & 7;
    const int j   = b >> 3;
    int bx, band;
    if constexpr (ORD == 0) {
        bx   = j % nN;
        band = (j / nN) * 8 + xcd;
    } else {
        const int BPX = (M / 128) >> 3;  // bands per XCD
        bx   = j / BPX;
        band = (j % BPX) * 8 + xcd;
    }

    const int m0 = band * 128;
    const int n0 = bx * TN;

    f32x4 acc[SM][4] = {};

    if constexpr (BK == 32) {
        const int srow = lane >> 2;          // 0..15
        const int scol = (lane & 3) * 8;
        const bf16* gA0 = A + (size_t)(m0 + wave * 32 + srow) * LDK + scol;
        const bf16* gA1 = gA0 + (size_t)16 * LDK;
        bf16* lA0 = &sA[(wave * 32) * 32];
        bf16* lA1 = &sA[(wave * 32 + 16) * 32];
        const bf16* gB0 = W + (size_t)(n0 + wave * (TN / 4) + srow) * LDK + scol;
        const bf16* gB1 = gB0 + (size_t)16 * LDK;
        bf16* lB0 = &sB[(wave * (TN / 4)) * 32];
        bf16* lB1 = &sB[(wave * (TN / 4) + 16) * 32];

        for (int k0 = 0; k0 < K; k0 += 32) {
            load16_lds(gA0 + k0, lA0);
            load16_lds(gA1 + k0, lA1);
            load16_lds(gB0 + k0, lB0);
            if constexpr (TN == 128) load16_lds(gB1 + k0, lB1);
            __syncthreads();

            bf16x8 af[SM], bfr[4];
#pragma unroll
            for (int s = 0; s < SM; ++s)
                af[s] = *reinterpret_cast<const bf16x8*>(&sA[(wm * (128 / WM) + s * 16 + l16) * 32 + quad * 8]);
#pragma unroll
            for (int t = 0; t < 4; ++t)
                bfr[t] = *reinterpret_cast<const bf16x8*>(&sB[(wn * 64 + t * 16 + l16) * 32 + quad * 8]);
#pragma unroll
            for (int s = 0; s < SM; ++s)
#pragma unroll
                for (int t = 0; t < 4; ++t)
                    acc[s][t] = __builtin_amdgcn_mfma_f32_16x16x32_bf16(af[s], bfr[t], acc[s][t], 0, 0, 0);
            __syncthreads();
        }
    } else {
        // BK == 64: swizzled staging. Each 1KB load covers 8 rows x 64 cols.
        const int lrow = lane >> 3;                    // 0..7
        const int lch  = ((lane & 7) ^ lrow) * 8;      // pre-swizzled global col chunk
        const bf16* gA = A + (size_t)(m0 + wave * 32 + lrow) * LDK + lch;
        const bf16* gB = W + (size_t)(n0 + wave * (TN / 4) + lrow) * LDK + lch;

        auto stageg = [&](int k0, int buf) {
            bf16* lA = smem + buf * BUFE + (wave * 32) * 64;
            bf16* lB = smem + buf * BUFE + 128 * BK + (wave * (TN / 4)) * 64;
#pragma unroll
            for (int i = 0; i < 4; ++i)
                load16_lds(gA + k0 + (size_t)(8 * i) * LDK, lA + 8 * i * 64);
#pragma unroll
            for (int i = 0; i < (TN / 4) / 8; ++i)
                load16_lds(gB + k0 + (size_t)(8 * i) * LDK, lB + 8 * i * 64);
        };
        auto comp = [&](int buf) {
            const bf16* cA = smem + buf * BUFE;
            const bf16* cB = cA + 128 * BK;
#pragma unroll
            for (int kk = 0; kk < 2; ++kk) {
                bf16x8 af[SM], bfr[4];
#pragma unroll
                for (int s = 0; s < SM; ++s) {
                    const int row = wm * (128 / WM) + s * 16 + l16;
                    const int sl  = (kk * 4 + quad) ^ (row & 7);
                    af[s] = *reinterpret_cast<const bf16x8*>(&cA[row * 64 + sl * 8]);
                }
#pragma unroll
                for (int t = 0; t < 4; ++t) {
                    const int row = wn * 64 + t * 16 + l16;
                    const int sl  = (kk * 4 + quad) ^ (row & 7);
                    bfr[t] = *reinterpret_cast<const bf16x8*>(&cB[row * 64 + sl * 8]);
                }
#pragma unroll
                for (int s = 0; s < SM; ++s)
#pragma unroll
                    for (int t = 0; t < 4; ++t)
                        acc[s][t] = __builtin_amdgcn_mfma_f32_16x16x32_bf16(af[s], bfr[t], acc[s][t], 0, 0, 0);
            }
        };

        if constexpr (PP) {
            // R12 counted-vmcnt ping-pong: NL = this wave's loads per stage.
            constexpr int NL = 4 + (TN / 4) / 8;   // TN=64 -> 6, TN=128 -> 8
            stageg(0, 0);
            stageg(64, 1);                          // K >= 128 always here
            int cur = 0;
            for (int k0 = 0; k0 < K; k0 += 64) {
                if (k0 + 64 < K)
                    asm volatile("s_waitcnt vmcnt(%0)" :: "i"(NL) : "memory");
                else
                    asm volatile("s_waitcnt vmcnt(0)" ::: "memory");
                __builtin_amdgcn_s_barrier();
                __builtin_amdgcn_sched_barrier(0);
                comp(cur);
                __builtin_amdgcn_s_barrier();       // all waves done reading cur
                __builtin_amdgcn_sched_barrier(0);
                if (k0 + 128 < K) stageg(k0 + 128, cur);
                cur ^= 1;
            }
        } else {
            for (int k0 = 0; k0 < K; k0 += 64) {
                stageg(k0, 0);
                __syncthreads();
                comp(0);
                __syncthreads();
            }
        }
    }

    if constexpr (EPI == 4) {
        if (n0 >= 2048) {
            // V columns: per-wave transpose through LDS (64x64, stride 72), store [B,H,dh,S]
            bf16* tw = &tbuf[wave * 64 * 72];
#pragma unroll
            for (int s = 0; s < SM; ++s)
#pragma unroll
                for (int t = 0; t < 4; ++t)
#pragma unroll
                    for (int r = 0; r < 4; ++r)
                        tw[(t * 16 + l16) * 72 + s * 16 + quad * 4 + r] = (bf16)acc[s][t][r];
#pragma unroll
            for (int i = 0; i < 8; ++i) {
                const int flat = i * 64 + lane;
                const int nl = flat >> 3;
                const int mc = flat & 7;
                bf16x8 v = *reinterpret_cast<const bf16x8*>(&tw[nl * 72 + mc * 8]);
                const int vcol = n0 - 2048 + wn * 64 + nl;
                const int m_glob = m0 + wm * 64 + mc * 8;
                const int bb = m_glob >> 11, sp = m_glob & (SEQ - 1);
                const int hh = vcol >> 6,  dh = vcol & 63;
                const size_t tidx = (((size_t)(bb * N_HEADS + hh) * D_HEAD + dh) << 11) + sp;
                *reinterpret_cast<bf16x8*>(&VT[tidx]) = v;
            }
        } else {
            // Q|K columns: row stride 2048; Q pre-scaled by 1/sqrt(dh)
            const float qscale = (n0 < 1024) ? 0.125f : 1.0f;
#pragma unroll
            for (int s = 0; s < SM; ++s) {
                const int mbase = m0 + wm * (128 / WM) + s * 16 + quad * 4;
#pragma unroll
                for (int t = 0; t < 4; ++t) {
                    const int n = n0 + wn * 64 + t * 16 + l16;
#pragma unroll
                    for (int r = 0; r < 4; ++r)
                        C[(size_t)(mbase + r) * 2048 + n] = (OutT)(acc[s][t][r] * qscale);
                }
            }
        }
    } else {
#pragma unroll
        for (int s = 0; s < SM; ++s) {
            const int mbase = m0 + wm * (128 / WM) + s * 16 + quad * 4;
#pragma unroll
            for (int t = 0; t < 4; ++t) {
                const int n = n0 + wn * 64 + t * 16 + l16;
#pragma unroll
                for (int r = 0; r < 4; ++r) {
                    float v = acc[s][t][r];
                    if (EPI == 1) v = gelu_f(v);
                    const size_t idx = (size_t)(mbase + r) * N + n;
                    if (EPI == 2) v += ADD[idx];
                    C[idx] = (OutT)v;
                }
            }
        }
    }
}

// ---------------- Flash attention: swapped QK^T + sigma-permuted K staging (R5) ----------------
// R10: + s_setprio(1) around MFMA clusters (T5) and defer-max rescale skip (T13, THR=8).
__global__ __launch_bounds__(256) void flash_attn_kernel(const bf16* __restrict__ qk,
                                                         const bf16* __restrict__ vt,
                                                         bf16* __restrict__ o) {
    const int id   = blockIdx.x;
    const int bhl  = id & 7;
    const int rest = id >> 3;
    const int pair = rest & 15;
    const int bhh  = rest >> 4;
    const int bh   = bhh * 8 + bhl;
    const int b    = bh >> 4;
    const int h    = bh & 15;
    const int wave = threadIdx.x >> 6;
    const int lane = threadIdx.x & 63;
    const int quad = lane >> 4;
    const int l16  = lane & 15;

    __shared__ __align__(16) bf16 sK[2][64 * 64];   // [buf][sigma-permuted key][dh]
    __shared__ __align__(16) bf16 sV[2][64 * 64];   // [buf][dh][key]

    const bf16* kbase = qk + (size_t)(b * SEQ) * 2048 + 1024 + h * D_HEAD;
    const bf16* vbase = vt + ((size_t)(bh * D_HEAD) << 11);   // [dh][S]

    const int lrow   = lane >> 3;              // 0..7
    const int lchunk = (lane & 7) ^ lrow;      // gather-side xor swizzle
    const int xr     = l16 & 7;                // read-side xor

    // sigma: LDS key-row i holds global key j0 + sigma(i)
    auto sig = [](int i) { return (i & 32) + (((i >> 2) & 3) << 3) + (((i >> 4) & 1) << 2) + (i & 3); };
    const int sg0 = sig(wave * 16 + lrow);
    const int sg1 = sig(wave * 16 + 8 + lrow);

    auto stage = [&](int j0, int buf) {
        const bf16* gk0 = kbase + (size_t)(j0 + sg0) * 2048 + lchunk * 8;
        const bf16* gk1 = kbase + (size_t)(j0 + sg1) * 2048 + lchunk * 8;
        const bf16* gv  = vbase + (size_t)(wave * 16 + lrow) * 2048 + j0 + lchunk * 8;
        load16_lds(gk0, &sK[buf][(wave * 16) * 64]);
        load16_lds(gk1, &sK[buf][(wave * 16 + 8) * 64]);
        load16_lds(gv,            &sV[buf][(wave * 16) * 64]);
        load16_lds(gv + 8 * 2048, &sV[buf][(wave * 16 + 8) * 64]);
    };

    for (int half = 0; half < 2; ++half) {
        const int qtile = half ? 31 - pair : pair;
        const int q0 = qtile * 64 + wave * 16;
        const int qg = q0 + l16;                         // this lane's q row
        const size_t qrow = (size_t)(b * SEQ + qg) * 2048 + h * D_HEAD;
        bf16x8 qf0 = *reinterpret_cast<const bf16x8*>(qk + qrow + quad * 8);
        bf16x8 qf1 = *reinterpret_cast<const bf16x8*>(qk + qrow + 32 + quad * 8);

        f32x4 o_acc[4] = {(f32x4)(0.f), (f32x4)(0.f), (f32x4)(0.f), (f32x4)(0.f)};
        float m_q = -1e30f;
        float l_r = 0.f;

        stage(0, 0);
        __syncthreads();

        for (int jt = 0; jt <= qtile; ++jt) {
            const int j0 = jt * 64;
            const int cur = jt & 1;
            if (jt < qtile) stage(j0 + 64, cur ^ 1);   // async prefetch into other buffer

            const bf16* sKc = sK[cur];
            const bf16* sVc = sV[cur];

            // S^T = K . Q^T : C[key-row][q-col=l16]
            f32x4 s_acc[4] = {(f32x4)(0.f), (f32x4)(0.f), (f32x4)(0.f), (f32x4)(0.f)};
            __builtin_amdgcn_s_setprio(1);
#pragma unroll
            for (int nb = 0; nb < 4; ++nb) {
                const int row = nb * 16 + l16;
                const int slot = quad ^ xr;
                bf16x8 kf0 = *reinterpret_cast<const bf16x8*>(&sKc[row * 64 + slot * 8]);
                bf16x8 kf1 = *reinterpret_cast<const bf16x8*>(&sKc[row * 64 + (slot ^ 4) * 8]);
                s_acc[nb] = __builtin_amdgcn_mfma_f32_16x16x32_bf16(kf0, qf0, s_acc[nb], 0, 0, 0);
                s_acc[nb] = __builtin_amdgcn_mfma_f32_16x16x32_bf16(kf1, qf1, s_acc[nb], 0, 0, 0);
            }
            __builtin_amdgcn_s_setprio(0);

            const bool diag = (jt == qtile);
            float p[4][4];
            float mx = -1e30f;
#pragma unroll
            for (int nb = 0; nb < 4; ++nb) {
#pragma unroll
                for (int r = 0; r < 4; ++r) {
                    float s = s_acc[nb][r];
                    if (diag) {
                        const int key = j0 + ((nb & 2) << 4) + (quad << 3) + ((nb & 1) << 2) + r;
                        if (key > qg) s = -1e30f;
                    }
                    p[nb][r] = s;
                    mx = fmaxf(mx, s);
                }
            }
            mx = fmaxf(mx, __shfl_xor(mx, 16, 64));
            mx = fmaxf(mx, __shfl_xor(mx, 32, 64));

            // T13 defer-max: only rescale when some q-row's max grew by > 8
            if (!__all(mx <= m_q + 8.0f)) {
                const float mn = fmaxf(m_q, mx);
                const float alpha = __expf(m_q - mn);
                m_q = mn;
                l_r *= alpha;
#pragma unroll
                for (int nb = 0; nb < 4; ++nb) o_acc[nb] *= alpha;
            }

            float ts = 0.f;
#pragma unroll
            for (int nb = 0; nb < 4; ++nb)
#pragma unroll
                for (int r = 0; r < 4; ++r) {
                    const float e = __expf(p[nb][r] - m_q);
                    p[nb][r] = e;
                    ts += e;
                }
            ts += __shfl_xor(ts, 16, 64);
            ts += __shfl_xor(ts, 32, 64);
            l_r += ts;

            bf16x8 pb0, pb1;
#pragma unroll
            for (int r = 0; r < 4; ++r) {
                pb0[r]     = (bf16)p[0][r];
                pb0[4 + r] = (bf16)p[1][r];
                pb1[r]     = (bf16)p[2][r];
                pb1[4 + r] = (bf16)p[3][r];
            }

            // O^T += V^T . P^T : A = V^T fragment, B = pb in regs
            __builtin_amdgcn_s_setprio(1);
#pragma unroll
            for (int nb = 0; nb < 4; ++nb) {
                const int row = nb * 16 + l16;
                const int slot = quad ^ xr;
                bf16x8 vf0 = *reinterpret_cast<const bf16x8*>(&sVc[row * 64 + slot * 8]);
                bf16x8 vf1 = *reinterpret_cast<const bf16x8*>(&sVc[row * 64 + (slot ^ 4) * 8]);
                o_acc[nb] = __builtin_amdgcn_mfma_f32_16x16x32_bf16(vf0, pb0, o_acc[nb], 0, 0, 0);
                o_acc[nb] = __builtin_amdgcn_mfma_f32_16x16x32_bf16(vf1, pb1, o_acc[nb], 0, 0, 0);
            }
            __builtin_amdgcn_s_setprio(0);
            __syncthreads();   // all waves done with cur; prefetch landed (vmcnt drain)
        }

        const float inv = 1.f / l_r;
#pragma unroll
        for (int nb = 0; nb < 4; ++nb) {
            bf16x4 ov;
#pragma unroll
            for (int r = 0; r < 4; ++r) ov[r] = (bf16)(o_acc[nb][r] * inv);
            *reinterpret_cast<bf16x4*>(
                &o[(size_t)(b * SEQ + qg) * D_MODEL + h * D_HEAD + nb * 16 + quad * 4]) = ov;
        }
    }
}

// ---------------- launch ----------------
// fp32 I/O. resid lives in d_out. Workspace (lifetime-aliased):
//   [0,24)   MB : bf16 weights wq|wk|wv (=wqkv) |wo|fc1|fc2
//   [24,40)  MB : n1 -> attn -> hid(start)
//   [40,72)  MB : qk [8192,2048] (dead after flash)
//   [72,88)  MB : vT (dead after flash)
//   MLP: if ws >= 104 MB: hid = [24,88), n2 = [88,104); else 2-chunk, n2 = [72,88).
extern "C" void kernel_launch(void* const* d_in, const int* in_sizes, int n_in,
                              void* d_out, int out_size, void* d_ws, size_t ws_size,
                              hipStream_t stream) {
    const float* x      = (const float*)d_in[0];
    const float* gamma1 = (const float*)d_in[1];
    const float* beta1  = (const float*)d_in[2];
    const float* wq     = (const float*)d_in[3];
    const float* wk     = (const float*)d_in[4];
    const float* wv     = (const float*)d_in[5];
    const float* wo     = (const float*)d_in[6];
    const float* gamma2 = (const float*)d_in[7];
    const float* beta2  = (const float*)d_in[8];
    const float* fc1    = (const float*)d_in[9];
    const float* fc2    = (const float*)d_in[10];
    float* out = (float*)d_out;

    const size_t WSMALL = (size_t)N_HEADS * D_HEAD * D_MODEL;  // 1,048,576
    const size_t WFF    = (size_t)D_FF * D_MODEL;              // 4,194,304
    const size_t RD     = (size_t)ROWS * D_MODEL;              // 8,388,608

    char* wsb = (char*)d_ws;
    bf16* wq_b  = (bf16*)(wsb);           // wq|wk|wv contiguous = wqkv [3072,1024]
    bf16* wk_b  = wq_b + WSMALL;
    bf16* wv_b  = wk_b + WSMALL;
    bf16* wo_b  = wv_b + WSMALL;
    bf16* fc1_b = wo_b + WSMALL;
    bf16* fc2_b = fc1_b + WFF;            // ends at 24 MB
    bf16* slotA = fc2_b + WFF;            // [24,40): n1 -> attn -> hid
    bf16* qkb   = slotA + RD;             // [40,72): q|k stride-2048
    bf16* vtb   = qkb + 2 * RD;           // [72,88)

    bf16* n1    = slotA;
    bf16* attnb = slotA;
    bf16* hid   = slotA;
    float* resid = out;

    const size_t need_single = (size_t)(24 + 64 + 16) * 1024 * 1024;
    const bool single = ws_size >= need_single;
    bf16* n2 = single ? (bf16*)(wsb + (size_t)88 * 1024 * 1024) : vtb;

    // weight conversion fp32 -> bf16
    f2b4_kernel<<<dim3(64, 4), 256, 0, stream>>>(wq, wk, wv, wo, wq_b, wk_b, wv_b, wo_b, (int)WSMALL);
    f2b2_kernel<<<dim3(256, 2), 256, 0, stream>>>(fc1, fc2, fc1_b, fc2_b, (int)WFF);

    // LN1
    ln_kernel<<<ROWS, 256, 0, stream>>>(x, gamma1, beta1, n1);
    // fused QKV: BK=64 swizzled + tbuf union (R4); ORD=1 (frozen bundle)
    gemm_mt<4, 128, 64, 1, bf16><<<(3072 / 128) * (ROWS / 128), 256, 0, stream>>>(n1, wq_b, qkb, nullptr, vtb, ROWS, 3072, D_MODEL, D_MODEL);
    // flash attention (R5 structure + R10 setprio/defer-max)
    flash_attn_kernel<<<1024, 256, 0, stream>>>(qkb, vtb, attnb);
    // resid(d_out) = x + attn @ wo^T — TN=64/ORD=0 + R12 counted-vmcnt PP
    gemm_mt<2, 64, 64, 0, float><<<(D_MODEL / 64) * (ROWS / 128), 256, 0, stream>>>(attnb, wo_b, resid, x, nullptr, ROWS, D_MODEL, D_MODEL, D_MODEL);
    // LN2
    ln_kernel<<<ROWS, 256, 0, stream>>>(resid, gamma2, beta2, n2);

    if (single) {
        // FC1: TN=128/BK=64/ORD=1 (frozen) + R12 counted-vmcnt PP (LDS 64KB)
        gemm_mt<1, 128, 64, 1, bf16><<<(D_FF / 128) * (ROWS / 128), 256, 0, stream>>>(n2, fc1_b, hid, nullptr, nullptr, ROWS, D_FF, D_MODEL, D_MODEL);
        // FC2: TN=64/ORD=0 + R12 counted-vmcnt PP (LDS 48KB)
        gemm_mt<2, 64, 64, 0, float><<<(D_MODEL / 64) * (ROWS / 128), 256, 0, stream>>>(hid, fc2_b, out, resid, nullptr, ROWS, D_MODEL, D_FF, D_FF);
    } else {
        const int CHUNK = 4096;   // hid chunk = 32 MB in [24,56); CHUNK/128 = 32 (div by 8 ok)
        for (int c = 0; c < ROWS / CHUNK; ++c) {
            const bf16*  n2c    = n2    + (size_t)c * CHUNK * D_MODEL;
            const float* residc = resid + (size_t)c * CHUNK * D_MODEL;
            float*       outc   = out   + (size_t)c * CHUNK * D_MODEL;
            gemm_mt<1, 128, 64, 1, bf16><<<(D_FF / 128) * (CHUNK / 128), 256, 0, stream>>>(n2c, fc1_b, hid, nullptr, nullptr, CHUNK, D_FF, D_MODEL, D_MODEL);
            gemm_mt<2, 64, 64, 0, float><<<(D_MODEL / 64) * (CHUNK / 128), 256, 0, stream>>>(hid, fc2_b, outc, residc, nullptr, CHUNK, D_MODEL, D_FF, D_FF);
        }
    }
}

// Round 13
// 490.490 us; speedup vs baseline: 1.0470x; 1.0207x over previous
//
#include <hip/hip_runtime.h>
#include <hip/hip_bf16.h>

#define D_MODEL 1024
#define N_HEADS 16
#define D_HEAD  64
#define D_FF    4096
#define BATCH   4
#define SEQ     2048
#define ROWS    (BATCH*SEQ)   // 8192
#define LN_EPS  1e-5f

typedef __bf16 bf16;
typedef __bf16 bf16x8 __attribute__((ext_vector_type(8)));
typedef __bf16 bf16x4 __attribute__((ext_vector_type(4)));
typedef float  f32x4  __attribute__((ext_vector_type(4)));

// ---- async global->LDS 16B copy: dst is WAVE-UNIFORM base, HW adds lane*16B ----
__device__ __forceinline__ void load16_lds(const bf16* g, bf16* l) {
#if defined(__has_builtin) && __has_builtin(__builtin_amdgcn_global_load_lds)
    __builtin_amdgcn_global_load_lds(
        (const __attribute__((address_space(1))) unsigned int*)g,
        (__attribute__((address_space(3))) unsigned int*)l,
        16, 0, 0);
#else
    const int lane = threadIdx.x & 63;
    ((bf16x8*)l)[lane] = *(const bf16x8*)g;
#endif
}

// ---------------- fp32 -> bf16 converts (batched, R13: float4/bf16x4 vectorized) ----------------
__global__ __launch_bounds__(256) void f2b4_kernel(const float* a, const float* b,
                                                   const float* c, const float* d,
                                                   bf16* oa, bf16* ob, bf16* oc, bf16* od,
                                                   int n) {
    const float* srcs[4] = {a, b, c, d};
    bf16* dsts[4] = {oa, ob, oc, od};
    const float* s = srcs[blockIdx.y];
    bf16* dst = dsts[blockIdx.y];
    const int nq = n >> 2;
    int i = blockIdx.x * 256 + threadIdx.x;
    int stride = gridDim.x * 256;
    for (; i < nq; i += stride) {
        float4 v = reinterpret_cast<const float4*>(s)[i];
        bf16x4 o;
        o[0] = (bf16)v.x; o[1] = (bf16)v.y; o[2] = (bf16)v.z; o[3] = (bf16)v.w;
        reinterpret_cast<bf16x4*>(dst)[i] = o;
    }
}
__global__ __launch_bounds__(256) void f2b2_kernel(const float* a, const float* b,
                                                   bf16* oa, bf16* ob, int n) {
    const float* s = blockIdx.y ? b : a;
    bf16* dst = blockIdx.y ? ob : oa;
    const int nq = n >> 2;
    int i = blockIdx.x * 256 + threadIdx.x;
    int stride = gridDim.x * 256;
    for (; i < nq; i += stride) {
        float4 v = reinterpret_cast<const float4*>(s)[i];
        bf16x4 o;
        o[0] = (bf16)v.x; o[1] = (bf16)v.y; o[2] = (bf16)v.z; o[3] = (bf16)v.w;
        reinterpret_cast<bf16x4*>(dst)[i] = o;
    }
}

// ---------------- LayerNorm: fp32 in -> bf16 out, one block per row ----------------
// R13: thread t owns cols [4t,4t+4): float4 loads (x, gamma, beta), bf16x4 store (G13).
__global__ __launch_bounds__(256) void ln_kernel(const float* __restrict__ x,
                                                 const float* __restrict__ gamma,
                                                 const float* __restrict__ beta,
                                                 bf16* __restrict__ out) {
    const int row = blockIdx.x;
    const int tid = threadIdx.x;
    const float* xr = x + (size_t)row * D_MODEL;

    const float4 v4 = *reinterpret_cast<const float4*>(xr + 4 * tid);
    float s  = v4.x + v4.y + v4.z + v4.w;
    float ss = v4.x * v4.x + v4.y * v4.y + v4.z * v4.z + v4.w * v4.w;
#pragma unroll
    for (int off = 32; off > 0; off >>= 1) {
        s  += __shfl_xor(s, off, 64);
        ss += __shfl_xor(ss, off, 64);
    }
    __shared__ float sbuf[4], ssbuf[4];
    const int wave = tid >> 6;
    if ((tid & 63) == 0) { sbuf[wave] = s; ssbuf[wave] = ss; }
    __syncthreads();
    s  = sbuf[0] + sbuf[1] + sbuf[2] + sbuf[3];
    ss = ssbuf[0] + ssbuf[1] + ssbuf[2] + ssbuf[3];

    const float mean = s * (1.f / D_MODEL);
    const float var  = ss * (1.f / D_MODEL) - mean * mean;
    const float inv  = rsqrtf(var + LN_EPS);

    const float4 g4 = *reinterpret_cast<const float4*>(gamma + 4 * tid);
    const float4 b4 = *reinterpret_cast<const float4*>(beta + 4 * tid);
    bf16x4 o4;
    o4[0] = (bf16)(g4.x * ((v4.x - mean) * inv) + b4.x);
    o4[1] = (bf16)(g4.y * ((v4.y - mean) * inv) + b4.y);
    o4[2] = (bf16)(g4.z * ((v4.z - mean) * inv) + b4.z);
    o4[3] = (bf16)(g4.w * ((v4.w - mean) * inv) + b4.w);
    *reinterpret_cast<bf16x4*>(out + (size_t)row * D_MODEL + 4 * tid) = o4;
}

// ---------------- GELU: 0.5x(1+tanh(y)) == x/(1+exp(-2y)), hardware v_exp_f32 ----------------
__device__ __forceinline__ float gelu_f(float x) {
    const float y = x * (0.7978845608f + 0.0356774081f * x * x);  // 0.7978845608*(x+0.044715x^3)
    return x / (1.f + __expf(-2.f * y));
}

// ---------------- GEMM m97-style, XCD-affine swizzle ----------------
// 1D grid.x of (N/TN)*(M/128) blocks. Block id b: xcd = b&7 (HW round-robin), j = b>>3.
// ORD=0 (band-outer): bx = j%nN, band = (j/nN)*8+xcd.
// ORD=1 (N-outer): bx = j/BPX, band = (j%BPX)*8+xcd; BPX=(M/128)/8.
// CONFIG FROZEN as the R7 bundle (R10 e2e 499.5): QKV ORD1, FC1 TN=128/ORD1,
// WO/FC2 TN=64/ORD0. R8/R9: per-dispatch times are NOT additive (L3 coupling);
// judge GEMM configs by e2e only; do not unbundle.
// STRUCTURE FROZEN as m97 2-barrier (R10): R11 drain0-PP (-12%: __syncthreads'
// vmcnt(0) drains the prefetch + 2x LDS halves occupancy) and R12 counted-vmcnt
// PP (FC2 100 vs 90 us: 2-deep window at 3 blk/CU < what 4-5 resident blocks of
// the simple structure hide) BOTH lost to occupancy-based cross-block overlap.
// Deeper pipelining needs the 512-thread 256^2 8-phase template (race-screen
// required); not attempted blind.
// BK=64: rows are 128B -> XOR chunk-swizzle (G4): global source pre-swizzled
//   (lane&7)^lrow so LDS dest stays linear (rule 21); read slot = chunk^(row&7).
//   SQ_LDS_BANK_CONFLICT = 0 since R3/R4.
// EPI: 0 plain; 1 gelu; 2 v += ADD[idx] fp32 (C may alias ADD);
//      4 fused-QKV: cols [0,2048) -> C row stride 2048 (q pre-scaled 1/8 | k),
//        cols [2048,3072) -> VT transposed [B,H,dh,S] via per-wave LDS (TN=128 only).
//        tbuf ALIASES sA/sB (union): only used after the K-loop's final barrier.
template <int EPI, int TN, int BK, int ORD, typename OutT>
__global__ __launch_bounds__(256) void gemm_mt(const bf16* __restrict__ A,
                                               const bf16* __restrict__ W,
                                               OutT* C,
                                               const float* ADD,
                                               bf16* VT,
                                               int M, int N, int K, int LDK) {
    constexpr int WN = TN / 64;          // waves along N
    constexpr int WM = 4 / WN;           // waves along M
    constexpr int SM = (128 / WM) / 16;  // M-subtiles per wave

    constexpr int AB_ELEMS = 128 * BK + TN * BK;
    constexpr int TB_ELEMS = (EPI == 4) ? 4 * 64 * 72 : 0;
    constexpr int SMEM_ELEMS = AB_ELEMS > TB_ELEMS ? AB_ELEMS : TB_ELEMS;
    __shared__ __align__(16) bf16 smem[SMEM_ELEMS];
    bf16* sA   = smem;
    bf16* sB   = smem + 128 * BK;
    bf16* tbuf = smem;                   // EPI==4 epilogue only (sA/sB dead by then)

    const int wave = threadIdx.x >> 6;
    const int lane = threadIdx.x & 63;
    const int quad = lane >> 4;
    const int l16  = lane & 15;
    const int wm   = wave / WN;
    const int wn   = wave % WN;

    // XCD-affine decode
    const int nN  = N / TN;
    const int b   = blockIdx.x;
    const int xcd = b & 7;
    const int j   = b >> 3;
    int bx, band;
    if constexpr (ORD == 0) {
        bx   = j % nN;
        band = (j / nN) * 8 + xcd;
    } else {
        const int BPX = (M / 128) >> 3;  // bands per XCD
        bx   = j / BPX;
        band = (j % BPX) * 8 + xcd;
    }

    const int m0 = band * 128;
    const int n0 = bx * TN;

    f32x4 acc[SM][4] = {};

    if constexpr (BK == 32) {
        const int srow = lane >> 2;          // 0..15
        const int scol = (lane & 3) * 8;
        const bf16* gA0 = A + (size_t)(m0 + wave * 32 + srow) * LDK + scol;
        const bf16* gA1 = gA0 + (size_t)16 * LDK;
        bf16* lA0 = &sA[(wave * 32) * 32];
        bf16* lA1 = &sA[(wave * 32 + 16) * 32];
        const bf16* gB0 = W + (size_t)(n0 + wave * (TN / 4) + srow) * LDK + scol;
        const bf16* gB1 = gB0 + (size_t)16 * LDK;
        bf16* lB0 = &sB[(wave * (TN / 4)) * 32];
        bf16* lB1 = &sB[(wave * (TN / 4) + 16) * 32];

        for (int k0 = 0; k0 < K; k0 += 32) {
            load16_lds(gA0 + k0, lA0);
            load16_lds(gA1 + k0, lA1);
            load16_lds(gB0 + k0, lB0);
            if constexpr (TN == 128) load16_lds(gB1 + k0, lB1);
            __syncthreads();

            bf16x8 af[SM], bfr[4];
#pragma unroll
            for (int s = 0; s < SM; ++s)
                af[s] = *reinterpret_cast<const bf16x8*>(&sA[(wm * (128 / WM) + s * 16 + l16) * 32 + quad * 8]);
#pragma unroll
            for (int t = 0; t < 4; ++t)
                bfr[t] = *reinterpret_cast<const bf16x8*>(&sB[(wn * 64 + t * 16 + l16) * 32 + quad * 8]);
#pragma unroll
            for (int s = 0; s < SM; ++s)
#pragma unroll
                for (int t = 0; t < 4; ++t)
                    acc[s][t] = __builtin_amdgcn_mfma_f32_16x16x32_bf16(af[s], bfr[t], acc[s][t], 0, 0, 0);
            __syncthreads();
        }
    } else {
        // BK == 64: swizzled staging. Each 1KB load covers 8 rows x 64 cols.
        const int lrow = lane >> 3;                    // 0..7
        const int lch  = ((lane & 7) ^ lrow) * 8;      // pre-swizzled global col chunk
        const bf16* gA = A + (size_t)(m0 + wave * 32 + lrow) * LDK + lch;
        bf16* lA = &sA[(wave * 32) * 64];
        const bf16* gB = W + (size_t)(n0 + wave * (TN / 4) + lrow) * LDK + lch;
        bf16* lB = &sB[(wave * (TN / 4)) * 64];

        for (int k0 = 0; k0 < K; k0 += 64) {
#pragma unroll
            for (int i = 0; i < 4; ++i)
                load16_lds(gA + k0 + (size_t)(8 * i) * LDK, lA + 8 * i * 64);
#pragma unroll
            for (int i = 0; i < (TN / 4) / 8; ++i)
                load16_lds(gB + k0 + (size_t)(8 * i) * LDK, lB + 8 * i * 64);
            __syncthreads();

#pragma unroll
            for (int kk = 0; kk < 2; ++kk) {
                bf16x8 af[SM], bfr[4];
#pragma unroll
                for (int s = 0; s < SM; ++s) {
                    const int row = wm * (128 / WM) + s * 16 + l16;
                    const int sl  = (kk * 4 + quad) ^ (row & 7);
                    af[s] = *reinterpret_cast<const bf16x8*>(&sA[row * 64 + sl * 8]);
                }
#pragma unroll
                for (int t = 0; t < 4; ++t) {
                    const int row = wn * 64 + t * 16 + l16;
                    const int sl  = (kk * 4 + quad) ^ (row & 7);
                    bfr[t] = *reinterpret_cast<const bf16x8*>(&sB[row * 64 + sl * 8]);
                }
#pragma unroll
                for (int s = 0; s < SM; ++s)
#pragma unroll
                    for (int t = 0; t < 4; ++t)
                        acc[s][t] = __builtin_amdgcn_mfma_f32_16x16x32_bf16(af[s], bfr[t], acc[s][t], 0, 0, 0);
            }
            __syncthreads();
        }
    }

    if constexpr (EPI == 4) {
        if (n0 >= 2048) {
            // V columns: per-wave transpose through LDS (64x64, stride 72), store [B,H,dh,S]
            bf16* tw = &tbuf[wave * 64 * 72];
#pragma unroll
            for (int s = 0; s < SM; ++s)
#pragma unroll
                for (int t = 0; t < 4; ++t)
#pragma unroll
                    for (int r = 0; r < 4; ++r)
                        tw[(t * 16 + l16) * 72 + s * 16 + quad * 4 + r] = (bf16)acc[s][t][r];
#pragma unroll
            for (int i = 0; i < 8; ++i) {
                const int flat = i * 64 + lane;
                const int nl = flat >> 3;
                const int mc = flat & 7;
                bf16x8 v = *reinterpret_cast<const bf16x8*>(&tw[nl * 72 + mc * 8]);
                const int vcol = n0 - 2048 + wn * 64 + nl;
                const int m_glob = m0 + wm * 64 + mc * 8;
                const int bb = m_glob >> 11, sp = m_glob & (SEQ - 1);
                const int hh = vcol >> 6,  dh = vcol & 63;
                const size_t tidx = (((size_t)(bb * N_HEADS + hh) * D_HEAD + dh) << 11) + sp;
                *reinterpret_cast<bf16x8*>(&VT[tidx]) = v;
            }
        } else {
            // Q|K columns: row stride 2048; Q pre-scaled by 1/sqrt(dh)
            const float qscale = (n0 < 1024) ? 0.125f : 1.0f;
#pragma unroll
            for (int s = 0; s < SM; ++s) {
                const int mbase = m0 + wm * (128 / WM) + s * 16 + quad * 4;
#pragma unroll
                for (int t = 0; t < 4; ++t) {
                    const int n = n0 + wn * 64 + t * 16 + l16;
#pragma unroll
                    for (int r = 0; r < 4; ++r)
                        C[(size_t)(mbase + r) * 2048 + n] = (OutT)(acc[s][t][r] * qscale);
                }
            }
        }
    } else {
#pragma unroll
        for (int s = 0; s < SM; ++s) {
            const int mbase = m0 + wm * (128 / WM) + s * 16 + quad * 4;
#pragma unroll
            for (int t = 0; t < 4; ++t) {
                const int n = n0 + wn * 64 + t * 16 + l16;
#pragma unroll
                for (int r = 0; r < 4; ++r) {
                    float v = acc[s][t][r];
                    if (EPI == 1) v = gelu_f(v);
                    const size_t idx = (size_t)(mbase + r) * N + n;
                    if (EPI == 2) v += ADD[idx];
                    C[idx] = (OutT)v;
                }
            }
        }
    }
}

// ---------------- Flash attention: swapped QK^T + sigma-permuted K staging (R5) ----------------
// R10: + s_setprio(1) around MFMA clusters (T5) and defer-max rescale skip (T13, THR=8).
__global__ __launch_bounds__(256) void flash_attn_kernel(const bf16* __restrict__ qk,
                                                         const bf16* __restrict__ vt,
                                                         bf16* __restrict__ o) {
    const int id   = blockIdx.x;
    const int bhl  = id & 7;
    const int rest = id >> 3;
    const int pair = rest & 15;
    const int bhh  = rest >> 4;
    const int bh   = bhh * 8 + bhl;
    const int b    = bh >> 4;
    const int h    = bh & 15;
    const int wave = threadIdx.x >> 6;
    const int lane = threadIdx.x & 63;
    const int quad = lane >> 4;
    const int l16  = lane & 15;

    __shared__ __align__(16) bf16 sK[2][64 * 64];   // [buf][sigma-permuted key][dh]
    __shared__ __align__(16) bf16 sV[2][64 * 64];   // [buf][dh][key]

    const bf16* kbase = qk + (size_t)(b * SEQ) * 2048 + 1024 + h * D_HEAD;
    const bf16* vbase = vt + ((size_t)(bh * D_HEAD) << 11);   // [dh][S]

    const int lrow   = lane >> 3;              // 0..7
    const int lchunk = (lane & 7) ^ lrow;      // gather-side xor swizzle
    const int xr     = l16 & 7;                // read-side xor

    // sigma: LDS key-row i holds global key j0 + sigma(i)
    auto sig = [](int i) { return (i & 32) + (((i >> 2) & 3) << 3) + (((i >> 4) & 1) << 2) + (i & 3); };
    const int sg0 = sig(wave * 16 + lrow);
    const int sg1 = sig(wave * 16 + 8 + lrow);

    auto stage = [&](int j0, int buf) {
        const bf16* gk0 = kbase + (size_t)(j0 + sg0) * 2048 + lchunk * 8;
        const bf16* gk1 = kbase + (size_t)(j0 + sg1) * 2048 + lchunk * 8;
        const bf16* gv  = vbase + (size_t)(wave * 16 + lrow) * 2048 + j0 + lchunk * 8;
        load16_lds(gk0, &sK[buf][(wave * 16) * 64]);
        load16_lds(gk1, &sK[buf][(wave * 16 + 8) * 64]);
        load16_lds(gv,            &sV[buf][(wave * 16) * 64]);
        load16_lds(gv + 8 * 2048, &sV[buf][(wave * 16 + 8) * 64]);
    };

    for (int half = 0; half < 2; ++half) {
        const int qtile = half ? 31 - pair : pair;
        const int q0 = qtile * 64 + wave * 16;
        const int qg = q0 + l16;                         // this lane's q row
        const size_t qrow = (size_t)(b * SEQ + qg) * 2048 + h * D_HEAD;
        bf16x8 qf0 = *reinterpret_cast<const bf16x8*>(qk + qrow + quad * 8);
        bf16x8 qf1 = *reinterpret_cast<const bf16x8*>(qk + qrow + 32 + quad * 8);

        f32x4 o_acc[4] = {(f32x4)(0.f), (f32x4)(0.f), (f32x4)(0.f), (f32x4)(0.f)};
        float m_q = -1e30f;
        float l_r = 0.f;

        stage(0, 0);
        __syncthreads();

        for (int jt = 0; jt <= qtile; ++jt) {
            const int j0 = jt * 64;
            const int cur = jt & 1;
            if (jt < qtile) stage(j0 + 64, cur ^ 1);   // async prefetch into other buffer

            const bf16* sKc = sK[cur];
            const bf16* sVc = sV[cur];

            // S^T = K . Q^T : C[key-row][q-col=l16]
            f32x4 s_acc[4] = {(f32x4)(0.f), (f32x4)(0.f), (f32x4)(0.f), (f32x4)(0.f)};
            __builtin_amdgcn_s_setprio(1);
#pragma unroll
            for (int nb = 0; nb < 4; ++nb) {
                const int row = nb * 16 + l16;
                const int slot = quad ^ xr;
                bf16x8 kf0 = *reinterpret_cast<const bf16x8*>(&sKc[row * 64 + slot * 8]);
                bf16x8 kf1 = *reinterpret_cast<const bf16x8*>(&sKc[row * 64 + (slot ^ 4) * 8]);
                s_acc[nb] = __builtin_amdgcn_mfma_f32_16x16x32_bf16(kf0, qf0, s_acc[nb], 0, 0, 0);
                s_acc[nb] = __builtin_amdgcn_mfma_f32_16x16x32_bf16(kf1, qf1, s_acc[nb], 0, 0, 0);
            }
            __builtin_amdgcn_s_setprio(0);

            const bool diag = (jt == qtile);
            float p[4][4];
            float mx = -1e30f;
#pragma unroll
            for (int nb = 0; nb < 4; ++nb) {
#pragma unroll
                for (int r = 0; r < 4; ++r) {
                    float s = s_acc[nb][r];
                    if (diag) {
                        const int key = j0 + ((nb & 2) << 4) + (quad << 3) + ((nb & 1) << 2) + r;
                        if (key > qg) s = -1e30f;
                    }
                    p[nb][r] = s;
                    mx = fmaxf(mx, s);
                }
            }
            mx = fmaxf(mx, __shfl_xor(mx, 16, 64));
            mx = fmaxf(mx, __shfl_xor(mx, 32, 64));

            // T13 defer-max: only rescale when some q-row's max grew by > 8
            if (!__all(mx <= m_q + 8.0f)) {
                const float mn = fmaxf(m_q, mx);
                const float alpha = __expf(m_q - mn);
                m_q = mn;
                l_r *= alpha;
#pragma unroll
                for (int nb = 0; nb < 4; ++nb) o_acc[nb] *= alpha;
            }

            float ts = 0.f;
#pragma unroll
            for (int nb = 0; nb < 4; ++nb)
#pragma unroll
                for (int r = 0; r < 4; ++r) {
                    const float e = __expf(p[nb][r] - m_q);
                    p[nb][r] = e;
                    ts += e;
                }
            ts += __shfl_xor(ts, 16, 64);
            ts += __shfl_xor(ts, 32, 64);
            l_r += ts;

            bf16x8 pb0, pb1;
#pragma unroll
            for (int r = 0; r < 4; ++r) {
                pb0[r]     = (bf16)p[0][r];
                pb0[4 + r] = (bf16)p[1][r];
                pb1[r]     = (bf16)p[2][r];
                pb1[4 + r] = (bf16)p[3][r];
            }

            // O^T += V^T . P^T : A = V^T fragment, B = pb in regs
            __builtin_amdgcn_s_setprio(1);
#pragma unroll
            for (int nb = 0; nb < 4; ++nb) {
                const int row = nb * 16 + l16;
                const int slot = quad ^ xr;
                bf16x8 vf0 = *reinterpret_cast<const bf16x8*>(&sVc[row * 64 + slot * 8]);
                bf16x8 vf1 = *reinterpret_cast<const bf16x8*>(&sVc[row * 64 + (slot ^ 4) * 8]);
                o_acc[nb] = __builtin_amdgcn_mfma_f32_16x16x32_bf16(vf0, pb0, o_acc[nb], 0, 0, 0);
                o_acc[nb] = __builtin_amdgcn_mfma_f32_16x16x32_bf16(vf1, pb1, o_acc[nb], 0, 0, 0);
            }
            __builtin_amdgcn_s_setprio(0);
            __syncthreads();   // all waves done with cur; prefetch landed (vmcnt drain)
        }

        const float inv = 1.f / l_r;
#pragma unroll
        for (int nb = 0; nb < 4; ++nb) {
            bf16x4 ov;
#pragma unroll
            for (int r = 0; r < 4; ++r) ov[r] = (bf16)(o_acc[nb][r] * inv);
            *reinterpret_cast<bf16x4*>(
                &o[(size_t)(b * SEQ + qg) * D_MODEL + h * D_HEAD + nb * 16 + quad * 4]) = ov;
        }
    }
}

// ---------------- launch ----------------
// fp32 I/O. resid lives in d_out. Workspace (lifetime-aliased):
//   [0,24)   MB : bf16 weights wq|wk|wv (=wqkv) |wo|fc1|fc2
//   [24,40)  MB : n1 -> attn -> hid(start)
//   [40,72)  MB : qk [8192,2048] (dead after flash)
//   [72,88)  MB : vT (dead after flash)
//   MLP: if ws >= 104 MB: hid = [24,88), n2 = [88,104); else 2-chunk, n2 = [72,88).
extern "C" void kernel_launch(void* const* d_in, const int* in_sizes, int n_in,
                              void* d_out, int out_size, void* d_ws, size_t ws_size,
                              hipStream_t stream) {
    const float* x      = (const float*)d_in[0];
    const float* gamma1 = (const float*)d_in[1];
    const float* beta1  = (const float*)d_in[2];
    const float* wq     = (const float*)d_in[3];
    const float* wk     = (const float*)d_in[4];
    const float* wv     = (const float*)d_in[5];
    const float* wo     = (const float*)d_in[6];
    const float* gamma2 = (const float*)d_in[7];
    const float* beta2  = (const float*)d_in[8];
    const float* fc1    = (const float*)d_in[9];
    const float* fc2    = (const float*)d_in[10];
    float* out = (float*)d_out;

    const size_t WSMALL = (size_t)N_HEADS * D_HEAD * D_MODEL;  // 1,048,576
    const size_t WFF    = (size_t)D_FF * D_MODEL;              // 4,194,304
    const size_t RD     = (size_t)ROWS * D_MODEL;              // 8,388,608

    char* wsb = (char*)d_ws;
    bf16* wq_b  = (bf16*)(wsb);           // wq|wk|wv contiguous = wqkv [3072,1024]
    bf16* wk_b  = wq_b + WSMALL;
    bf16* wv_b  = wk_b + WSMALL;
    bf16* wo_b  = wv_b + WSMALL;
    bf16* fc1_b = wo_b + WSMALL;
    bf16* fc2_b = fc1_b + WFF;            // ends at 24 MB
    bf16* slotA = fc2_b + WFF;            // [24,40): n1 -> attn -> hid
    bf16* qkb   = slotA + RD;             // [40,72): q|k stride-2048
    bf16* vtb   = qkb + 2 * RD;           // [72,88)

    bf16* n1    = slotA;
    bf16* attnb = slotA;
    bf16* hid   = slotA;
    float* resid = out;

    const size_t need_single = (size_t)(24 + 64 + 16) * 1024 * 1024;
    const bool single = ws_size >= need_single;
    bf16* n2 = single ? (bf16*)(wsb + (size_t)88 * 1024 * 1024) : vtb;

    // weight conversion fp32 -> bf16 (R13 vectorized)
    f2b4_kernel<<<dim3(64, 4), 256, 0, stream>>>(wq, wk, wv, wo, wq_b, wk_b, wv_b, wo_b, (int)WSMALL);
    f2b2_kernel<<<dim3(256, 2), 256, 0, stream>>>(fc1, fc2, fc1_b, fc2_b, (int)WFF);

    // LN1
    ln_kernel<<<ROWS, 256, 0, stream>>>(x, gamma1, beta1, n1);
    // fused QKV: BK=64 swizzled + tbuf union (R4); ORD=1 (frozen bundle)
    gemm_mt<4, 128, 64, 1, bf16><<<(3072 / 128) * (ROWS / 128), 256, 0, stream>>>(n1, wq_b, qkb, nullptr, vtb, ROWS, 3072, D_MODEL, D_MODEL);
    // flash attention (R5 structure + R10 setprio/defer-max)
    flash_attn_kernel<<<1024, 256, 0, stream>>>(qkb, vtb, attnb);
    // resid(d_out) = x + attn @ wo^T — TN=64/ORD=0, m97 structure (R13 revert)
    gemm_mt<2, 64, 64, 0, float><<<(D_MODEL / 64) * (ROWS / 128), 256, 0, stream>>>(attnb, wo_b, resid, x, nullptr, ROWS, D_MODEL, D_MODEL, D_MODEL);
    // LN2
    ln_kernel<<<ROWS, 256, 0, stream>>>(resid, gamma2, beta2, n2);

    if (single) {
        // FC1: TN=128/BK=64/ORD=1 (frozen bundle), m97 structure
        gemm_mt<1, 128, 64, 1, bf16><<<(D_FF / 128) * (ROWS / 128), 256, 0, stream>>>(n2, fc1_b, hid, nullptr, nullptr, ROWS, D_FF, D_MODEL, D_MODEL);
        // FC2: TN=64/ORD=0, m97 structure
        gemm_mt<2, 64, 64, 0, float><<<(D_MODEL / 64) * (ROWS / 128), 256, 0, stream>>>(hid, fc2_b, out, resid, nullptr, ROWS, D_MODEL, D_FF, D_FF);
    } else {
        const int CHUNK = 4096;   // hid chunk = 32 MB in [24,56); CHUNK/128 = 32 (div by 8 ok)
        for (int c = 0; c < ROWS / CHUNK; ++c) {
            const bf16*  n2c    = n2    + (size_t)c * CHUNK * D_MODEL;
            const float* residc = resid + (size_t)c * CHUNK * D_MODEL;
            float*       outc   = out   + (size_t)c * CHUNK * D_MODEL;
            gemm_mt<1, 128, 64, 1, bf16><<<(D_FF / 128) * (CHUNK / 128), 256, 0, stream>>>(n2c, fc1_b, hid, nullptr, nullptr, CHUNK, D_FF, D_MODEL, D_MODEL);
            gemm_mt<2, 64, 64, 0, float><<<(D_MODEL / 64) * (CHUNK / 128), 256, 0, stream>>>(hid, fc2_b, outc, residc, nullptr, CHUNK, D_MODEL, D_FF, D_FF);
        }
    }
}

// Round 14
// 482.625 us; speedup vs baseline: 1.0641x; 1.0163x over previous
//
#include <hip/hip_runtime.h>
#include <hip/hip_bf16.h>

#define D_MODEL 1024
#define N_HEADS 16
#define D_HEAD  64
#define D_FF    4096
#define BATCH   4
#define SEQ     2048
#define ROWS    (BATCH*SEQ)   // 8192
#define LN_EPS  1e-5f

typedef __bf16 bf16;
typedef __bf16 bf16x8 __attribute__((ext_vector_type(8)));
typedef __bf16 bf16x4 __attribute__((ext_vector_type(4)));
typedef float  f32x4  __attribute__((ext_vector_type(4)));

// ---- async global->LDS 16B copy: dst is WAVE-UNIFORM base, HW adds lane*16B ----
__device__ __forceinline__ void load16_lds(const bf16* g, bf16* l) {
#if defined(__has_builtin) && __has_builtin(__builtin_amdgcn_global_load_lds)
    __builtin_amdgcn_global_load_lds(
        (const __attribute__((address_space(1))) unsigned int*)g,
        (__attribute__((address_space(3))) unsigned int*)l,
        16, 0, 0);
#else
    const int lane = threadIdx.x & 63;
    ((bf16x8*)l)[lane] = *(const bf16x8*)g;
#endif
}

// ---------------- LN row body (shared by prep_kernel and ln_kernel) ----------------
// Thread t owns cols [4t,4t+4): float4 loads (x, gamma, beta), bf16x4 store (G13).
__device__ __forceinline__ void ln_row(const float* __restrict__ x,
                                       const float* __restrict__ gamma,
                                       const float* __restrict__ beta,
                                       bf16* __restrict__ out, int row, int tid) {
    const float* xr = x + (size_t)row * D_MODEL;
    const float4 v4 = *reinterpret_cast<const float4*>(xr + 4 * tid);
    float s  = v4.x + v4.y + v4.z + v4.w;
    float ss = v4.x * v4.x + v4.y * v4.y + v4.z * v4.z + v4.w * v4.w;
#pragma unroll
    for (int off = 32; off > 0; off >>= 1) {
        s  += __shfl_xor(s, off, 64);
        ss += __shfl_xor(ss, off, 64);
    }
    __shared__ float sbuf[4], ssbuf[4];
    const int wave = tid >> 6;
    if ((tid & 63) == 0) { sbuf[wave] = s; ssbuf[wave] = ss; }
    __syncthreads();
    s  = sbuf[0] + sbuf[1] + sbuf[2] + sbuf[3];
    ss = ssbuf[0] + ssbuf[1] + ssbuf[2] + ssbuf[3];

    const float mean = s * (1.f / D_MODEL);
    const float var  = ss * (1.f / D_MODEL) - mean * mean;
    const float inv  = rsqrtf(var + LN_EPS);

    const float4 g4 = *reinterpret_cast<const float4*>(gamma + 4 * tid);
    const float4 b4 = *reinterpret_cast<const float4*>(beta + 4 * tid);
    bf16x4 o4;
    o4[0] = (bf16)(g4.x * ((v4.x - mean) * inv) + b4.x);
    o4[1] = (bf16)(g4.y * ((v4.y - mean) * inv) + b4.y);
    o4[2] = (bf16)(g4.z * ((v4.z - mean) * inv) + b4.z);
    o4[3] = (bf16)(g4.w * ((v4.w - mean) * inv) + b4.w);
    *reinterpret_cast<bf16x4*>(out + (size_t)row * D_MODEL + 4 * tid) = o4;
}

// ---------------- prep: ALL weight converts + LN1 in ONE dispatch (R14) ----------------
// Blocks [0, CONVB): six fp32->bf16 converts via a flat segmented float4 index space.
// Destinations are CONTIGUOUS in workspace (wq|wk|wv|wo|fc1|fc2), so dst f4 idx == q.
// Blocks [CONVB, CONVB+ROWS): LN1 rows. All independent; everything completes before
// QKV by stream order. Saves 2 launches + their tail gaps.
#define CONVB 1024
__global__ __launch_bounds__(256) void prep_kernel(const float* __restrict__ wq,
                                                   const float* __restrict__ wk,
                                                   const float* __restrict__ wv,
                                                   const float* __restrict__ wo,
                                                   const float* __restrict__ fc1,
                                                   const float* __restrict__ fc2,
                                                   bf16* __restrict__ wdst,
                                                   const float* __restrict__ x,
                                                   const float* __restrict__ gamma1,
                                                   const float* __restrict__ beta1,
                                                   bf16* __restrict__ n1) {
    const int bid = blockIdx.x;
    if (bid >= CONVB) {
        ln_row(x, gamma1, beta1, n1, bid - CONVB, threadIdx.x);
        return;
    }
    // converts: S = WSMALL/4 f4 per small array, L = WFF/4 per big array
    constexpr int S  = (N_HEADS * D_HEAD * D_MODEL) / 4;   // 262144
    constexpr int L  = (D_FF * D_MODEL) / 4;               // 1048576
    constexpr int NT = 4 * S + 2 * L;                      // 3145728 total f4
    const float* smalls[4] = {wq, wk, wv, wo};
    bf16x4* dst4 = reinterpret_cast<bf16x4*>(wdst);
    const int stride = CONVB * 256;
    for (int q = bid * 256 + threadIdx.x; q < NT; q += stride) {
        const float* src; int off;
        if (q < 4 * S) { src = smalls[q >> 18]; off = q & (S - 1); }
        else {
            int r = q - 4 * S;
            src = (r < L) ? fc1 : fc2;
            off = (r < L) ? r : r - L;
        }
        float4 v = reinterpret_cast<const float4*>(src)[off];
        bf16x4 o;
        o[0] = (bf16)v.x; o[1] = (bf16)v.y; o[2] = (bf16)v.z; o[3] = (bf16)v.w;
        dst4[q] = o;
    }
}

// ---------------- LayerNorm (standalone, used for LN2) ----------------
__global__ __launch_bounds__(256) void ln_kernel(const float* __restrict__ x,
                                                 const float* __restrict__ gamma,
                                                 const float* __restrict__ beta,
                                                 bf16* __restrict__ out) {
    ln_row(x, gamma, beta, out, blockIdx.x, threadIdx.x);
}

// ---------------- GELU: 0.5x(1+tanh(y)) == x/(1+exp(-2y)), hardware v_exp_f32 ----------------
__device__ __forceinline__ float gelu_f(float x) {
    const float y = x * (0.7978845608f + 0.0356774081f * x * x);  // 0.7978845608*(x+0.044715x^3)
    return x / (1.f + __expf(-2.f * y));
}

// ---------------- GEMM m97-style, XCD-affine swizzle ----------------
// 1D grid.x of (N/TN)*(M/128) blocks. Block id b: xcd = b&7 (HW round-robin), j = b>>3.
// ORD=0 (band-outer): bx = j%nN, band = (j/nN)*8+xcd.
// ORD=1 (N-outer): bx = j/BPX, band = (j%BPX)*8+xcd; BPX=(M/128)/8.
// CONFIG FROZEN as the R7 bundle (R13 e2e 490.5): QKV ORD1, FC1 TN=128/ORD1,
// WO/FC2 TN=64/ORD0. R8/R9: per-dispatch times are NOT additive (L3 coupling);
// judge GEMM configs by e2e only; do not unbundle.
// STRUCTURE FROZEN as m97 2-barrier (R13): R11 drain0-PP (-12%) and R12
// counted-vmcnt PP (FC2 100 vs 90) BOTH lost to occupancy-based cross-block
// overlap at these tile shapes. Deeper pipelining needs the 512-thread 256^2
// 8-phase template (race-screen required); not attempted blind.
// BK=64: rows are 128B -> XOR chunk-swizzle (G4): global source pre-swizzled
//   (lane&7)^lrow so LDS dest stays linear (rule 21); read slot = chunk^(row&7).
//   SQ_LDS_BANK_CONFLICT = 0 since R3/R4.
// EPI: 0 plain; 1 gelu; 2 v += ADD[idx] fp32 (C may alias ADD);
//      4 fused-QKV: cols [0,2048) -> C row stride 2048 (q pre-scaled 1/8 | k),
//        cols [2048,3072) -> VT transposed [B,H,dh,S] via per-wave LDS (TN=128 only).
//        tbuf ALIASES sA/sB (union): only used after the K-loop's final barrier.
template <int EPI, int TN, int BK, int ORD, typename OutT>
__global__ __launch_bounds__(256) void gemm_mt(const bf16* __restrict__ A,
                                               const bf16* __restrict__ W,
                                               OutT* C,
                                               const float* ADD,
                                               bf16* VT,
                                               int M, int N, int K, int LDK) {
    constexpr int WN = TN / 64;          // waves along N
    constexpr int WM = 4 / WN;           // waves along M
    constexpr int SM = (128 / WM) / 16;  // M-subtiles per wave

    constexpr int AB_ELEMS = 128 * BK + TN * BK;
    constexpr int TB_ELEMS = (EPI == 4) ? 4 * 64 * 72 : 0;
    constexpr int SMEM_ELEMS = AB_ELEMS > TB_ELEMS ? AB_ELEMS : TB_ELEMS;
    __shared__ __align__(16) bf16 smem[SMEM_ELEMS];
    bf16* sA   = smem;
    bf16* sB   = smem + 128 * BK;
    bf16* tbuf = smem;                   // EPI==4 epilogue only (sA/sB dead by then)

    const int wave = threadIdx.x >> 6;
    const int lane = threadIdx.x & 63;
    const int quad = lane >> 4;
    const int l16  = lane & 15;
    const int wm   = wave / WN;
    const int wn   = wave % WN;

    // XCD-affine decode
    const int nN  = N / TN;
    const int b   = blockIdx.x;
    const int xcd = b & 7;
    const int j   = b >> 3;
    int bx, band;
    if constexpr (ORD == 0) {
        bx   = j % nN;
        band = (j / nN) * 8 + xcd;
    } else {
        const int BPX = (M / 128) >> 3;  // bands per XCD
        bx   = j / BPX;
        band = (j % BPX) * 8 + xcd;
    }

    const int m0 = band * 128;
    const int n0 = bx * TN;

    f32x4 acc[SM][4] = {};

    if constexpr (BK == 32) {
        const int srow = lane >> 2;          // 0..15
        const int scol = (lane & 3) * 8;
        const bf16* gA0 = A + (size_t)(m0 + wave * 32 + srow) * LDK + scol;
        const bf16* gA1 = gA0 + (size_t)16 * LDK;
        bf16* lA0 = &sA[(wave * 32) * 32];
        bf16* lA1 = &sA[(wave * 32 + 16) * 32];
        const bf16* gB0 = W + (size_t)(n0 + wave * (TN / 4) + srow) * LDK + scol;
        const bf16* gB1 = gB0 + (size_t)16 * LDK;
        bf16* lB0 = &sB[(wave * (TN / 4)) * 32];
        bf16* lB1 = &sB[(wave * (TN / 4) + 16) * 32];

        for (int k0 = 0; k0 < K; k0 += 32) {
            load16_lds(gA0 + k0, lA0);
            load16_lds(gA1 + k0, lA1);
            load16_lds(gB0 + k0, lB0);
            if constexpr (TN == 128) load16_lds(gB1 + k0, lB1);
            __syncthreads();

            bf16x8 af[SM], bfr[4];
#pragma unroll
            for (int s = 0; s < SM; ++s)
                af[s] = *reinterpret_cast<const bf16x8*>(&sA[(wm * (128 / WM) + s * 16 + l16) * 32 + quad * 8]);
#pragma unroll
            for (int t = 0; t < 4; ++t)
                bfr[t] = *reinterpret_cast<const bf16x8*>(&sB[(wn * 64 + t * 16 + l16) * 32 + quad * 8]);
#pragma unroll
            for (int s = 0; s < SM; ++s)
#pragma unroll
                for (int t = 0; t < 4; ++t)
                    acc[s][t] = __builtin_amdgcn_mfma_f32_16x16x32_bf16(af[s], bfr[t], acc[s][t], 0, 0, 0);
            __syncthreads();
        }
    } else {
        // BK == 64: swizzled staging. Each 1KB load covers 8 rows x 64 cols.
        const int lrow = lane >> 3;                    // 0..7
        const int lch  = ((lane & 7) ^ lrow) * 8;      // pre-swizzled global col chunk
        const bf16* gA = A + (size_t)(m0 + wave * 32 + lrow) * LDK + lch;
        bf16* lA = &sA[(wave * 32) * 64];
        const bf16* gB = W + (size_t)(n0 + wave * (TN / 4) + lrow) * LDK + lch;
        bf16* lB = &sB[(wave * (TN / 4)) * 64];

        for (int k0 = 0; k0 < K; k0 += 64) {
#pragma unroll
            for (int i = 0; i < 4; ++i)
                load16_lds(gA + k0 + (size_t)(8 * i) * LDK, lA + 8 * i * 64);
#pragma unroll
            for (int i = 0; i < (TN / 4) / 8; ++i)
                load16_lds(gB + k0 + (size_t)(8 * i) * LDK, lB + 8 * i * 64);
            __syncthreads();

#pragma unroll
            for (int kk = 0; kk < 2; ++kk) {
                bf16x8 af[SM], bfr[4];
#pragma unroll
                for (int s = 0; s < SM; ++s) {
                    const int row = wm * (128 / WM) + s * 16 + l16;
                    const int sl  = (kk * 4 + quad) ^ (row & 7);
                    af[s] = *reinterpret_cast<const bf16x8*>(&sA[row * 64 + sl * 8]);
                }
#pragma unroll
                for (int t = 0; t < 4; ++t) {
                    const int row = wn * 64 + t * 16 + l16;
                    const int sl  = (kk * 4 + quad) ^ (row & 7);
                    bfr[t] = *reinterpret_cast<const bf16x8*>(&sB[row * 64 + sl * 8]);
                }
#pragma unroll
                for (int s = 0; s < SM; ++s)
#pragma unroll
                    for (int t = 0; t < 4; ++t)
                        acc[s][t] = __builtin_amdgcn_mfma_f32_16x16x32_bf16(af[s], bfr[t], acc[s][t], 0, 0, 0);
            }
            __syncthreads();
        }
    }

    if constexpr (EPI == 4) {
        if (n0 >= 2048) {
            // V columns: per-wave transpose through LDS (64x64, stride 72), store [B,H,dh,S]
            bf16* tw = &tbuf[wave * 64 * 72];
#pragma unroll
            for (int s = 0; s < SM; ++s)
#pragma unroll
                for (int t = 0; t < 4; ++t)
#pragma unroll
                    for (int r = 0; r < 4; ++r)
                        tw[(t * 16 + l16) * 72 + s * 16 + quad * 4 + r] = (bf16)acc[s][t][r];
#pragma unroll
            for (int i = 0; i < 8; ++i) {
                const int flat = i * 64 + lane;
                const int nl = flat >> 3;
                const int mc = flat & 7;
                bf16x8 v = *reinterpret_cast<const bf16x8*>(&tw[nl * 72 + mc * 8]);
                const int vcol = n0 - 2048 + wn * 64 + nl;
                const int m_glob = m0 + wm * 64 + mc * 8;
                const int bb = m_glob >> 11, sp = m_glob & (SEQ - 1);
                const int hh = vcol >> 6,  dh = vcol & 63;
                const size_t tidx = (((size_t)(bb * N_HEADS + hh) * D_HEAD + dh) << 11) + sp;
                *reinterpret_cast<bf16x8*>(&VT[tidx]) = v;
            }
        } else {
            // Q|K columns: row stride 2048; Q pre-scaled by 1/sqrt(dh)
            const float qscale = (n0 < 1024) ? 0.125f : 1.0f;
#pragma unroll
            for (int s = 0; s < SM; ++s) {
                const int mbase = m0 + wm * (128 / WM) + s * 16 + quad * 4;
#pragma unroll
                for (int t = 0; t < 4; ++t) {
                    const int n = n0 + wn * 64 + t * 16 + l16;
#pragma unroll
                    for (int r = 0; r < 4; ++r)
                        C[(size_t)(mbase + r) * 2048 + n] = (OutT)(acc[s][t][r] * qscale);
                }
            }
        }
    } else {
#pragma unroll
        for (int s = 0; s < SM; ++s) {
            const int mbase = m0 + wm * (128 / WM) + s * 16 + quad * 4;
#pragma unroll
            for (int t = 0; t < 4; ++t) {
                const int n = n0 + wn * 64 + t * 16 + l16;
#pragma unroll
                for (int r = 0; r < 4; ++r) {
                    float v = acc[s][t][r];
                    if (EPI == 1) v = gelu_f(v);
                    const size_t idx = (size_t)(mbase + r) * N + n;
                    if (EPI == 2) v += ADD[idx];
                    C[idx] = (OutT)v;
                }
            }
        }
    }
}

// ---------------- Flash attention: swapped QK^T + sigma-permuted K staging (R5) ----------------
// R10: + s_setprio(1) around MFMA clusters (T5) and defer-max rescale skip (T13, THR=8).
__global__ __launch_bounds__(256) void flash_attn_kernel(const bf16* __restrict__ qk,
                                                         const bf16* __restrict__ vt,
                                                         bf16* __restrict__ o) {
    const int id   = blockIdx.x;
    const int bhl  = id & 7;
    const int rest = id >> 3;
    const int pair = rest & 15;
    const int bhh  = rest >> 4;
    const int bh   = bhh * 8 + bhl;
    const int b    = bh >> 4;
    const int h    = bh & 15;
    const int wave = threadIdx.x >> 6;
    const int lane = threadIdx.x & 63;
    const int quad = lane >> 4;
    const int l16  = lane & 15;

    __shared__ __align__(16) bf16 sK[2][64 * 64];   // [buf][sigma-permuted key][dh]
    __shared__ __align__(16) bf16 sV[2][64 * 64];   // [buf][dh][key]

    const bf16* kbase = qk + (size_t)(b * SEQ) * 2048 + 1024 + h * D_HEAD;
    const bf16* vbase = vt + ((size_t)(bh * D_HEAD) << 11);   // [dh][S]

    const int lrow   = lane >> 3;              // 0..7
    const int lchunk = (lane & 7) ^ lrow;      // gather-side xor swizzle
    const int xr     = l16 & 7;                // read-side xor

    // sigma: LDS key-row i holds global key j0 + sigma(i)
    auto sig = [](int i) { return (i & 32) + (((i >> 2) & 3) << 3) + (((i >> 4) & 1) << 2) + (i & 3); };
    const int sg0 = sig(wave * 16 + lrow);
    const int sg1 = sig(wave * 16 + 8 + lrow);

    auto stage = [&](int j0, int buf) {
        const bf16* gk0 = kbase + (size_t)(j0 + sg0) * 2048 + lchunk * 8;
        const bf16* gk1 = kbase + (size_t)(j0 + sg1) * 2048 + lchunk * 8;
        const bf16* gv  = vbase + (size_t)(wave * 16 + lrow) * 2048 + j0 + lchunk * 8;
        load16_lds(gk0, &sK[buf][(wave * 16) * 64]);
        load16_lds(gk1, &sK[buf][(wave * 16 + 8) * 64]);
        load16_lds(gv,            &sV[buf][(wave * 16) * 64]);
        load16_lds(gv + 8 * 2048, &sV[buf][(wave * 16 + 8) * 64]);
    };

    for (int half = 0; half < 2; ++half) {
        const int qtile = half ? 31 - pair : pair;
        const int q0 = qtile * 64 + wave * 16;
        const int qg = q0 + l16;                         // this lane's q row
        const size_t qrow = (size_t)(b * SEQ + qg) * 2048 + h * D_HEAD;
        bf16x8 qf0 = *reinterpret_cast<const bf16x8*>(qk + qrow + quad * 8);
        bf16x8 qf1 = *reinterpret_cast<const bf16x8*>(qk + qrow + 32 + quad * 8);

        f32x4 o_acc[4] = {(f32x4)(0.f), (f32x4)(0.f), (f32x4)(0.f), (f32x4)(0.f)};
        float m_q = -1e30f;
        float l_r = 0.f;

        stage(0, 0);
        __syncthreads();

        for (int jt = 0; jt <= qtile; ++jt) {
            const int j0 = jt * 64;
            const int cur = jt & 1;
            if (jt < qtile) stage(j0 + 64, cur ^ 1);   // async prefetch into other buffer

            const bf16* sKc = sK[cur];
            const bf16* sVc = sV[cur];

            // S^T = K . Q^T : C[key-row][q-col=l16]
            f32x4 s_acc[4] = {(f32x4)(0.f), (f32x4)(0.f), (f32x4)(0.f), (f32x4)(0.f)};
            __builtin_amdgcn_s_setprio(1);
#pragma unroll
            for (int nb = 0; nb < 4; ++nb) {
                const int row = nb * 16 + l16;
                const int slot = quad ^ xr;
                bf16x8 kf0 = *reinterpret_cast<const bf16x8*>(&sKc[row * 64 + slot * 8]);
                bf16x8 kf1 = *reinterpret_cast<const bf16x8*>(&sKc[row * 64 + (slot ^ 4) * 8]);
                s_acc[nb] = __builtin_amdgcn_mfma_f32_16x16x32_bf16(kf0, qf0, s_acc[nb], 0, 0, 0);
                s_acc[nb] = __builtin_amdgcn_mfma_f32_16x16x32_bf16(kf1, qf1, s_acc[nb], 0, 0, 0);
            }
            __builtin_amdgcn_s_setprio(0);

            const bool diag = (jt == qtile);
            float p[4][4];
            float mx = -1e30f;
#pragma unroll
            for (int nb = 0; nb < 4; ++nb) {
#pragma unroll
                for (int r = 0; r < 4; ++r) {
                    float s = s_acc[nb][r];
                    if (diag) {
                        const int key = j0 + ((nb & 2) << 4) + (quad << 3) + ((nb & 1) << 2) + r;
                        if (key > qg) s = -1e30f;
                    }
                    p[nb][r] = s;
                    mx = fmaxf(mx, s);
                }
            }
            mx = fmaxf(mx, __shfl_xor(mx, 16, 64));
            mx = fmaxf(mx, __shfl_xor(mx, 32, 64));

            // T13 defer-max: only rescale when some q-row's max grew by > 8
            if (!__all(mx <= m_q + 8.0f)) {
                const float mn = fmaxf(m_q, mx);
                const float alpha = __expf(m_q - mn);
                m_q = mn;
                l_r *= alpha;
#pragma unroll
                for (int nb = 0; nb < 4; ++nb) o_acc[nb] *= alpha;
            }

            float ts = 0.f;
#pragma unroll
            for (int nb = 0; nb < 4; ++nb)
#pragma unroll
                for (int r = 0; r < 4; ++r) {
                    const float e = __expf(p[nb][r] - m_q);
                    p[nb][r] = e;
                    ts += e;
                }
            ts += __shfl_xor(ts, 16, 64);
            ts += __shfl_xor(ts, 32, 64);
            l_r += ts;

            bf16x8 pb0, pb1;
#pragma unroll
            for (int r = 0; r < 4; ++r) {
                pb0[r]     = (bf16)p[0][r];
                pb0[4 + r] = (bf16)p[1][r];
                pb1[r]     = (bf16)p[2][r];
                pb1[4 + r] = (bf16)p[3][r];
            }

            // O^T += V^T . P^T : A = V^T fragment, B = pb in regs
            __builtin_amdgcn_s_setprio(1);
#pragma unroll
            for (int nb = 0; nb < 4; ++nb) {
                const int row = nb * 16 + l16;
                const int slot = quad ^ xr;
                bf16x8 vf0 = *reinterpret_cast<const bf16x8*>(&sVc[row * 64 + slot * 8]);
                bf16x8 vf1 = *reinterpret_cast<const bf16x8*>(&sVc[row * 64 + (slot ^ 4) * 8]);
                o_acc[nb] = __builtin_amdgcn_mfma_f32_16x16x32_bf16(vf0, pb0, o_acc[nb], 0, 0, 0);
                o_acc[nb] = __builtin_amdgcn_mfma_f32_16x16x32_bf16(vf1, pb1, o_acc[nb], 0, 0, 0);
            }
            __builtin_amdgcn_s_setprio(0);
            __syncthreads();   // all waves done with cur; prefetch landed (vmcnt drain)
        }

        const float inv = 1.f / l_r;
#pragma unroll
        for (int nb = 0; nb < 4; ++nb) {
            bf16x4 ov;
#pragma unroll
            for (int r = 0; r < 4; ++r) ov[r] = (bf16)(o_acc[nb][r] * inv);
            *reinterpret_cast<bf16x4*>(
                &o[(size_t)(b * SEQ + qg) * D_MODEL + h * D_HEAD + nb * 16 + quad * 4]) = ov;
        }
    }
}

// ---------------- launch ----------------
// fp32 I/O. resid lives in d_out. Workspace (lifetime-aliased):
//   [0,24)   MB : bf16 weights wq|wk|wv (=wqkv) |wo|fc1|fc2
//   [24,40)  MB : n1 -> attn -> hid(start)
//   [40,72)  MB : qk [8192,2048] (dead after flash)
//   [72,88)  MB : vT (dead after flash)
//   MLP: if ws >= 104 MB: hid = [24,88), n2 = [88,104); else 2-chunk, n2 = [72,88).
extern "C" void kernel_launch(void* const* d_in, const int* in_sizes, int n_in,
                              void* d_out, int out_size, void* d_ws, size_t ws_size,
                              hipStream_t stream) {
    const float* x      = (const float*)d_in[0];
    const float* gamma1 = (const float*)d_in[1];
    const float* beta1  = (const float*)d_in[2];
    const float* wq     = (const float*)d_in[3];
    const float* wk     = (const float*)d_in[4];
    const float* wv     = (const float*)d_in[5];
    const float* wo     = (const float*)d_in[6];
    const float* gamma2 = (const float*)d_in[7];
    const float* beta2  = (const float*)d_in[8];
    const float* fc1    = (const float*)d_in[9];
    const float* fc2    = (const float*)d_in[10];
    float* out = (float*)d_out;

    const size_t WSMALL = (size_t)N_HEADS * D_HEAD * D_MODEL;  // 1,048,576
    const size_t WFF    = (size_t)D_FF * D_MODEL;              // 4,194,304
    const size_t RD     = (size_t)ROWS * D_MODEL;              // 8,388,608

    char* wsb = (char*)d_ws;
    bf16* wq_b  = (bf16*)(wsb);           // wq|wk|wv contiguous = wqkv [3072,1024]
    bf16* wk_b  = wq_b + WSMALL;
    bf16* wv_b  = wk_b + WSMALL;
    bf16* wo_b  = wv_b + WSMALL;
    bf16* fc1_b = wo_b + WSMALL;
    bf16* fc2_b = fc1_b + WFF;            // ends at 24 MB
    bf16* slotA = fc2_b + WFF;            // [24,40): n1 -> attn -> hid
    bf16* qkb   = slotA + RD;             // [40,72): q|k stride-2048
    bf16* vtb   = qkb + 2 * RD;           // [72,88)

    bf16* n1    = slotA;
    bf16* attnb = slotA;
    bf16* hid   = slotA;
    float* resid = out;

    const size_t need_single = (size_t)(24 + 64 + 16) * 1024 * 1024;
    const bool single = ws_size >= need_single;
    bf16* n2 = single ? (bf16*)(wsb + (size_t)88 * 1024 * 1024) : vtb;

    // prep: all six weight converts + LN1 in one dispatch (R14)
    prep_kernel<<<CONVB + ROWS, 256, 0, stream>>>(wq, wk, wv, wo, fc1, fc2, wq_b,
                                                  x, gamma1, beta1, n1);
    // fused QKV: BK=64 swizzled + tbuf union (R4); ORD=1 (frozen bundle)
    gemm_mt<4, 128, 64, 1, bf16><<<(3072 / 128) * (ROWS / 128), 256, 0, stream>>>(n1, wq_b, qkb, nullptr, vtb, ROWS, 3072, D_MODEL, D_MODEL);
    // flash attention (R5 structure + R10 setprio/defer-max)
    flash_attn_kernel<<<1024, 256, 0, stream>>>(qkb, vtb, attnb);
    // resid(d_out) = x + attn @ wo^T — TN=64/ORD=0, m97 structure
    gemm_mt<2, 64, 64, 0, float><<<(D_MODEL / 64) * (ROWS / 128), 256, 0, stream>>>(attnb, wo_b, resid, x, nullptr, ROWS, D_MODEL, D_MODEL, D_MODEL);
    // LN2
    ln_kernel<<<ROWS, 256, 0, stream>>>(resid, gamma2, beta2, n2);

    if (single) {
        // FC1: TN=128/BK=64/ORD=1 (frozen bundle), m97 structure
        gemm_mt<1, 128, 64, 1, bf16><<<(D_FF / 128) * (ROWS / 128), 256, 0, stream>>>(n2, fc1_b, hid, nullptr, nullptr, ROWS, D_FF, D_MODEL, D_MODEL);
        // FC2: TN=64/ORD=0, m97 structure
        gemm_mt<2, 64, 64, 0, float><<<(D_MODEL / 64) * (ROWS / 128), 256, 0, stream>>>(hid, fc2_b, out, resid, nullptr, ROWS, D_MODEL, D_FF, D_FF);
    } else {
        const int CHUNK = 4096;   // hid chunk = 32 MB in [24,56); CHUNK/128 = 32 (div by 8 ok)
        for (int c = 0; c < ROWS / CHUNK; ++c) {
            const bf16*  n2c    = n2    + (size_t)c * CHUNK * D_MODEL;
            const float* residc = resid + (size_t)c * CHUNK * D_MODEL;
            float*       outc   = out   + (size_t)c * CHUNK * D_MODEL;
            gemm_mt<1, 128, 64, 1, bf16><<<(D_FF / 128) * (CHUNK / 128), 256, 0, stream>>>(n2c, fc1_b, hid, nullptr, nullptr, CHUNK, D_FF, D_MODEL, D_MODEL);
            gemm_mt<2, 64, 64, 0, float><<<(D_MODEL / 64) * (CHUNK / 128), 256, 0, stream>>>(hid, fc2_b, outc, residc, nullptr, CHUNK, D_MODEL, D_FF, D_FF);
        }
    }
}

// Round 15
// 478.462 us; speedup vs baseline: 1.0733x; 1.0087x over previous
//
#include <hip/hip_runtime.h>
#include <hip/hip_bf16.h>

#define D_MODEL 1024
#define N_HEADS 16
#define D_HEAD  64
#define D_FF    4096
#define BATCH   4
#define SEQ     2048
#define ROWS    (BATCH*SEQ)   // 8192
#define LN_EPS  1e-5f

typedef __bf16 bf16;
typedef __bf16 bf16x8 __attribute__((ext_vector_type(8)));
typedef __bf16 bf16x4 __attribute__((ext_vector_type(4)));
typedef float  f32x4  __attribute__((ext_vector_type(4)));

// ---- async global->LDS 16B copy: dst is WAVE-UNIFORM base, HW adds lane*16B ----
__device__ __forceinline__ void load16_lds(const bf16* g, bf16* l) {
#if defined(__has_builtin) && __has_builtin(__builtin_amdgcn_global_load_lds)
    __builtin_amdgcn_global_load_lds(
        (const __attribute__((address_space(1))) unsigned int*)g,
        (__attribute__((address_space(3))) unsigned int*)l,
        16, 0, 0);
#else
    const int lane = threadIdx.x & 63;
    ((bf16x8*)l)[lane] = *(const bf16x8*)g;
#endif
}

// ---------------- LN row body (shared by prep_kernel and ln_kernel) ----------------
// Thread t owns cols [4t,4t+4): float4 loads (x, gamma, beta), bf16x4 store (G13).
__device__ __forceinline__ void ln_row(const float* __restrict__ x,
                                       const float* __restrict__ gamma,
                                       const float* __restrict__ beta,
                                       bf16* __restrict__ out, int row, int tid) {
    const float* xr = x + (size_t)row * D_MODEL;
    const float4 v4 = *reinterpret_cast<const float4*>(xr + 4 * tid);
    float s  = v4.x + v4.y + v4.z + v4.w;
    float ss = v4.x * v4.x + v4.y * v4.y + v4.z * v4.z + v4.w * v4.w;
#pragma unroll
    for (int off = 32; off > 0; off >>= 1) {
        s  += __shfl_xor(s, off, 64);
        ss += __shfl_xor(ss, off, 64);
    }
    __shared__ float sbuf[4], ssbuf[4];
    const int wave = tid >> 6;
    if ((tid & 63) == 0) { sbuf[wave] = s; ssbuf[wave] = ss; }
    __syncthreads();
    s  = sbuf[0] + sbuf[1] + sbuf[2] + sbuf[3];
    ss = ssbuf[0] + ssbuf[1] + ssbuf[2] + ssbuf[3];

    const float mean = s * (1.f / D_MODEL);
    const float var  = ss * (1.f / D_MODEL) - mean * mean;
    const float inv  = rsqrtf(var + LN_EPS);

    const float4 g4 = *reinterpret_cast<const float4*>(gamma + 4 * tid);
    const float4 b4 = *reinterpret_cast<const float4*>(beta + 4 * tid);
    bf16x4 o4;
    o4[0] = (bf16)(g4.x * ((v4.x - mean) * inv) + b4.x);
    o4[1] = (bf16)(g4.y * ((v4.y - mean) * inv) + b4.y);
    o4[2] = (bf16)(g4.z * ((v4.z - mean) * inv) + b4.z);
    o4[3] = (bf16)(g4.w * ((v4.w - mean) * inv) + b4.w);
    *reinterpret_cast<bf16x4*>(out + (size_t)row * D_MODEL + 4 * tid) = o4;
}

// ---------------- prep: ALL weight converts + LN1 in ONE dispatch (R14) ----------------
// Blocks [0, CONVB): six fp32->bf16 converts via a flat segmented float4 index space.
// Destinations are CONTIGUOUS in workspace (wq|wk|wv|wo|fc1|fc2), so dst f4 idx == q.
// Blocks [CONVB, CONVB+ROWS): LN1 rows. All independent; everything completes before
// QKV by stream order. Saves 2 launches + their tail gaps.
#define CONVB 1024
__global__ __launch_bounds__(256) void prep_kernel(const float* __restrict__ wq,
                                                   const float* __restrict__ wk,
                                                   const float* __restrict__ wv,
                                                   const float* __restrict__ wo,
                                                   const float* __restrict__ fc1,
                                                   const float* __restrict__ fc2,
                                                   bf16* __restrict__ wdst,
                                                   const float* __restrict__ x,
                                                   const float* __restrict__ gamma1,
                                                   const float* __restrict__ beta1,
                                                   bf16* __restrict__ n1) {
    const int bid = blockIdx.x;
    if (bid >= CONVB) {
        ln_row(x, gamma1, beta1, n1, bid - CONVB, threadIdx.x);
        return;
    }
    // converts: S = WSMALL/4 f4 per small array, L = WFF/4 per big array
    constexpr int S  = (N_HEADS * D_HEAD * D_MODEL) / 4;   // 262144
    constexpr int L  = (D_FF * D_MODEL) / 4;               // 1048576
    constexpr int NT = 4 * S + 2 * L;                      // 3145728 total f4
    const float* smalls[4] = {wq, wk, wv, wo};
    bf16x4* dst4 = reinterpret_cast<bf16x4*>(wdst);
    const int stride = CONVB * 256;
    for (int q = bid * 256 + threadIdx.x; q < NT; q += stride) {
        const float* src; int off;
        if (q < 4 * S) { src = smalls[q >> 18]; off = q & (S - 1); }
        else {
            int r = q - 4 * S;
            src = (r < L) ? fc1 : fc2;
            off = (r < L) ? r : r - L;
        }
        float4 v = reinterpret_cast<const float4*>(src)[off];
        bf16x4 o;
        o[0] = (bf16)v.x; o[1] = (bf16)v.y; o[2] = (bf16)v.z; o[3] = (bf16)v.w;
        dst4[q] = o;
    }
}

// ---------------- LayerNorm (standalone, used for LN2) ----------------
__global__ __launch_bounds__(256) void ln_kernel(const float* __restrict__ x,
                                                 const float* __restrict__ gamma,
                                                 const float* __restrict__ beta,
                                                 bf16* __restrict__ out) {
    ln_row(x, gamma, beta, out, blockIdx.x, threadIdx.x);
}

// ---------------- GELU: 0.5x(1+tanh(y)) == x/(1+exp(-2y)), hardware v_exp_f32 ----------------
__device__ __forceinline__ float gelu_f(float x) {
    const float y = x * (0.7978845608f + 0.0356774081f * x * x);  // 0.7978845608*(x+0.044715x^3)
    return x / (1.f + __expf(-2.f * y));
}

// ---------------- GEMM m97-style, XCD-affine swizzle ----------------
// 1D grid.x of (N/TN)*(M/128) blocks. Block id b: xcd = b&7 (HW round-robin), j = b>>3.
// ORD=0 (band-outer): bx = j%nN, band = (j/nN)*8+xcd.
// ORD=1 (N-outer): bx = j/BPX, band = (j%BPX)*8+xcd; BPX=(M/128)/8.
// CONFIG FROZEN as the R7 bundle (R14 e2e 482.6): QKV ORD1, FC1 TN=128/ORD1,
// WO/FC2 TN=64/ORD0. R8/R9: per-dispatch times are NOT additive (L3 coupling);
// judge GEMM configs by e2e only; do not unbundle.
// STRUCTURE FROZEN as m97 2-barrier (R13): R11 drain0-PP (-12%) and R12
// counted-vmcnt PP (FC2 100 vs 90) BOTH lost to occupancy-based cross-block
// overlap at these tile shapes. Deeper pipelining needs the 512-thread 256^2
// 8-phase template (race-screen required); not attempted blind.
// BK=64: rows are 128B -> XOR chunk-swizzle (G4): global source pre-swizzled
//   (lane&7)^lrow so LDS dest stays linear (rule 21); read slot = chunk^(row&7).
//   SQ_LDS_BANK_CONFLICT = 0 since R3/R4.
// EPI: 0 plain; 1 gelu; 2 v += ADD[idx] fp32 (C may alias ADD);
//      4 fused-QKV: cols [0,2048) -> C row stride 2048 (q pre-scaled 1/8 | k),
//        cols [2048,3072) -> VT transposed [B,H,dh,S] via per-wave LDS (TN=128 only).
//        tbuf ALIASES sA/sB (union): only used after the K-loop's final barrier.
template <int EPI, int TN, int BK, int ORD, typename OutT>
__global__ __launch_bounds__(256) void gemm_mt(const bf16* __restrict__ A,
                                               const bf16* __restrict__ W,
                                               OutT* C,
                                               const float* ADD,
                                               bf16* VT,
                                               int M, int N, int K, int LDK) {
    constexpr int WN = TN / 64;          // waves along N
    constexpr int WM = 4 / WN;           // waves along M
    constexpr int SM = (128 / WM) / 16;  // M-subtiles per wave

    constexpr int AB_ELEMS = 128 * BK + TN * BK;
    constexpr int TB_ELEMS = (EPI == 4) ? 4 * 64 * 72 : 0;
    constexpr int SMEM_ELEMS = AB_ELEMS > TB_ELEMS ? AB_ELEMS : TB_ELEMS;
    __shared__ __align__(16) bf16 smem[SMEM_ELEMS];
    bf16* sA   = smem;
    bf16* sB   = smem + 128 * BK;
    bf16* tbuf = smem;                   // EPI==4 epilogue only (sA/sB dead by then)

    const int wave = threadIdx.x >> 6;
    const int lane = threadIdx.x & 63;
    const int quad = lane >> 4;
    const int l16  = lane & 15;
    const int wm   = wave / WN;
    const int wn   = wave % WN;

    // XCD-affine decode
    const int nN  = N / TN;
    const int b   = blockIdx.x;
    const int xcd = b & 7;
    const int j   = b >> 3;
    int bx, band;
    if constexpr (ORD == 0) {
        bx   = j % nN;
        band = (j / nN) * 8 + xcd;
    } else {
        const int BPX = (M / 128) >> 3;  // bands per XCD
        bx   = j / BPX;
        band = (j % BPX) * 8 + xcd;
    }

    const int m0 = band * 128;
    const int n0 = bx * TN;

    f32x4 acc[SM][4] = {};

    if constexpr (BK == 32) {
        const int srow = lane >> 2;          // 0..15
        const int scol = (lane & 3) * 8;
        const bf16* gA0 = A + (size_t)(m0 + wave * 32 + srow) * LDK + scol;
        const bf16* gA1 = gA0 + (size_t)16 * LDK;
        bf16* lA0 = &sA[(wave * 32) * 32];
        bf16* lA1 = &sA[(wave * 32 + 16) * 32];
        const bf16* gB0 = W + (size_t)(n0 + wave * (TN / 4) + srow) * LDK + scol;
        const bf16* gB1 = gB0 + (size_t)16 * LDK;
        bf16* lB0 = &sB[(wave * (TN / 4)) * 32];
        bf16* lB1 = &sB[(wave * (TN / 4) + 16) * 32];

        for (int k0 = 0; k0 < K; k0 += 32) {
            load16_lds(gA0 + k0, lA0);
            load16_lds(gA1 + k0, lA1);
            load16_lds(gB0 + k0, lB0);
            if constexpr (TN == 128) load16_lds(gB1 + k0, lB1);
            __syncthreads();

            bf16x8 af[SM], bfr[4];
#pragma unroll
            for (int s = 0; s < SM; ++s)
                af[s] = *reinterpret_cast<const bf16x8*>(&sA[(wm * (128 / WM) + s * 16 + l16) * 32 + quad * 8]);
#pragma unroll
            for (int t = 0; t < 4; ++t)
                bfr[t] = *reinterpret_cast<const bf16x8*>(&sB[(wn * 64 + t * 16 + l16) * 32 + quad * 8]);
#pragma unroll
            for (int s = 0; s < SM; ++s)
#pragma unroll
                for (int t = 0; t < 4; ++t)
                    acc[s][t] = __builtin_amdgcn_mfma_f32_16x16x32_bf16(af[s], bfr[t], acc[s][t], 0, 0, 0);
            __syncthreads();
        }
    } else {
        // BK == 64: swizzled staging. Each 1KB load covers 8 rows x 64 cols.
        const int lrow = lane >> 3;                    // 0..7
        const int lch  = ((lane & 7) ^ lrow) * 8;      // pre-swizzled global col chunk
        const bf16* gA = A + (size_t)(m0 + wave * 32 + lrow) * LDK + lch;
        bf16* lA = &sA[(wave * 32) * 64];
        const bf16* gB = W + (size_t)(n0 + wave * (TN / 4) + lrow) * LDK + lch;
        bf16* lB = &sB[(wave * (TN / 4)) * 64];

        for (int k0 = 0; k0 < K; k0 += 64) {
#pragma unroll
            for (int i = 0; i < 4; ++i)
                load16_lds(gA + k0 + (size_t)(8 * i) * LDK, lA + 8 * i * 64);
#pragma unroll
            for (int i = 0; i < (TN / 4) / 8; ++i)
                load16_lds(gB + k0 + (size_t)(8 * i) * LDK, lB + 8 * i * 64);
            __syncthreads();

#pragma unroll
            for (int kk = 0; kk < 2; ++kk) {
                bf16x8 af[SM], bfr[4];
#pragma unroll
                for (int s = 0; s < SM; ++s) {
                    const int row = wm * (128 / WM) + s * 16 + l16;
                    const int sl  = (kk * 4 + quad) ^ (row & 7);
                    af[s] = *reinterpret_cast<const bf16x8*>(&sA[row * 64 + sl * 8]);
                }
#pragma unroll
                for (int t = 0; t < 4; ++t) {
                    const int row = wn * 64 + t * 16 + l16;
                    const int sl  = (kk * 4 + quad) ^ (row & 7);
                    bfr[t] = *reinterpret_cast<const bf16x8*>(&sB[row * 64 + sl * 8]);
                }
#pragma unroll
                for (int s = 0; s < SM; ++s)
#pragma unroll
                    for (int t = 0; t < 4; ++t)
                        acc[s][t] = __builtin_amdgcn_mfma_f32_16x16x32_bf16(af[s], bfr[t], acc[s][t], 0, 0, 0);
            }
            __syncthreads();
        }
    }

    if constexpr (EPI == 4) {
        if (n0 >= 2048) {
            // V columns: per-wave transpose through LDS (64x64, stride 72), store [B,H,dh,S]
            bf16* tw = &tbuf[wave * 64 * 72];
#pragma unroll
            for (int s = 0; s < SM; ++s)
#pragma unroll
                for (int t = 0; t < 4; ++t)
#pragma unroll
                    for (int r = 0; r < 4; ++r)
                        tw[(t * 16 + l16) * 72 + s * 16 + quad * 4 + r] = (bf16)acc[s][t][r];
#pragma unroll
            for (int i = 0; i < 8; ++i) {
                const int flat = i * 64 + lane;
                const int nl = flat >> 3;
                const int mc = flat & 7;
                bf16x8 v = *reinterpret_cast<const bf16x8*>(&tw[nl * 72 + mc * 8]);
                const int vcol = n0 - 2048 + wn * 64 + nl;
                const int m_glob = m0 + wm * 64 + mc * 8;
                const int bb = m_glob >> 11, sp = m_glob & (SEQ - 1);
                const int hh = vcol >> 6,  dh = vcol & 63;
                const size_t tidx = (((size_t)(bb * N_HEADS + hh) * D_HEAD + dh) << 11) + sp;
                *reinterpret_cast<bf16x8*>(&VT[tidx]) = v;
            }
        } else {
            // Q|K columns: row stride 2048; Q pre-scaled by 1/sqrt(dh)
            const float qscale = (n0 < 1024) ? 0.125f : 1.0f;
#pragma unroll
            for (int s = 0; s < SM; ++s) {
                const int mbase = m0 + wm * (128 / WM) + s * 16 + quad * 4;
#pragma unroll
                for (int t = 0; t < 4; ++t) {
                    const int n = n0 + wn * 64 + t * 16 + l16;
#pragma unroll
                    for (int r = 0; r < 4; ++r)
                        C[(size_t)(mbase + r) * 2048 + n] = (OutT)(acc[s][t][r] * qscale);
                }
            }
        }
    } else {
#pragma unroll
        for (int s = 0; s < SM; ++s) {
            const int mbase = m0 + wm * (128 / WM) + s * 16 + quad * 4;
#pragma unroll
            for (int t = 0; t < 4; ++t) {
                const int n = n0 + wn * 64 + t * 16 + l16;
#pragma unroll
                for (int r = 0; r < 4; ++r) {
                    float v = acc[s][t][r];
                    if (EPI == 1) v = gelu_f(v);
                    const size_t idx = (size_t)(mbase + r) * N + n;
                    if (EPI == 2) v += ADD[idx];
                    C[idx] = (OutT)v;
                }
            }
        }
    }
}

// ---------------- Flash attention: swapped QK^T + sigma-permuted K staging (R5) ----------------
// R10: + s_setprio(1) around MFMA clusters (T5) and defer-max rescale skip (T13, THR=8).
// R15: one q-tile per block (grid 2048, was 1024 with a 2-half loop). LDS = 32768 B
// allows 5 blocks/CU but the old grid capped residency at 4; splitting lifts the cap
// and lets short (low-qtile) blocks back-fill. id = bhl + 8*(qt + 32*bhh): bhl keeps
// the head->XCD round-robin (KV L2 locality); per-tile math/masking unchanged.
__global__ __launch_bounds__(256) void flash_attn_kernel(const bf16* __restrict__ qk,
                                                         const bf16* __restrict__ vt,
                                                         bf16* __restrict__ o) {
    const int id   = blockIdx.x;
    const int bhl  = id & 7;
    const int rest = id >> 3;
    const int qt   = rest & 31;
    const int bhh  = rest >> 5;
    const int bh   = bhh * 8 + bhl;
    const int b    = bh >> 4;
    const int h    = bh & 15;
    const int wave = threadIdx.x >> 6;
    const int lane = threadIdx.x & 63;
    const int quad = lane >> 4;
    const int l16  = lane & 15;

    __shared__ __align__(16) bf16 sK[2][64 * 64];   // [buf][sigma-permuted key][dh]
    __shared__ __align__(16) bf16 sV[2][64 * 64];   // [buf][dh][key]

    const bf16* kbase = qk + (size_t)(b * SEQ) * 2048 + 1024 + h * D_HEAD;
    const bf16* vbase = vt + ((size_t)(bh * D_HEAD) << 11);   // [dh][S]

    const int lrow   = lane >> 3;              // 0..7
    const int lchunk = (lane & 7) ^ lrow;      // gather-side xor swizzle
    const int xr     = l16 & 7;                // read-side xor

    // sigma: LDS key-row i holds global key j0 + sigma(i)
    auto sig = [](int i) { return (i & 32) + (((i >> 2) & 3) << 3) + (((i >> 4) & 1) << 2) + (i & 3); };
    const int sg0 = sig(wave * 16 + lrow);
    const int sg1 = sig(wave * 16 + 8 + lrow);

    auto stage = [&](int j0, int buf) {
        const bf16* gk0 = kbase + (size_t)(j0 + sg0) * 2048 + lchunk * 8;
        const bf16* gk1 = kbase + (size_t)(j0 + sg1) * 2048 + lchunk * 8;
        const bf16* gv  = vbase + (size_t)(wave * 16 + lrow) * 2048 + j0 + lchunk * 8;
        load16_lds(gk0, &sK[buf][(wave * 16) * 64]);
        load16_lds(gk1, &sK[buf][(wave * 16 + 8) * 64]);
        load16_lds(gv,            &sV[buf][(wave * 16) * 64]);
        load16_lds(gv + 8 * 2048, &sV[buf][(wave * 16 + 8) * 64]);
    };

    {
        const int qtile = qt;
        const int q0 = qtile * 64 + wave * 16;
        const int qg = q0 + l16;                         // this lane's q row
        const size_t qrow = (size_t)(b * SEQ + qg) * 2048 + h * D_HEAD;
        bf16x8 qf0 = *reinterpret_cast<const bf16x8*>(qk + qrow + quad * 8);
        bf16x8 qf1 = *reinterpret_cast<const bf16x8*>(qk + qrow + 32 + quad * 8);

        f32x4 o_acc[4] = {(f32x4)(0.f), (f32x4)(0.f), (f32x4)(0.f), (f32x4)(0.f)};
        float m_q = -1e30f;
        float l_r = 0.f;

        stage(0, 0);
        __syncthreads();

        for (int jt = 0; jt <= qtile; ++jt) {
            const int j0 = jt * 64;
            const int cur = jt & 1;
            if (jt < qtile) stage(j0 + 64, cur ^ 1);   // async prefetch into other buffer

            const bf16* sKc = sK[cur];
            const bf16* sVc = sV[cur];

            // S^T = K . Q^T : C[key-row][q-col=l16]
            f32x4 s_acc[4] = {(f32x4)(0.f), (f32x4)(0.f), (f32x4)(0.f), (f32x4)(0.f)};
            __builtin_amdgcn_s_setprio(1);
#pragma unroll
            for (int nb = 0; nb < 4; ++nb) {
                const int row = nb * 16 + l16;
                const int slot = quad ^ xr;
                bf16x8 kf0 = *reinterpret_cast<const bf16x8*>(&sKc[row * 64 + slot * 8]);
                bf16x8 kf1 = *reinterpret_cast<const bf16x8*>(&sKc[row * 64 + (slot ^ 4) * 8]);
                s_acc[nb] = __builtin_amdgcn_mfma_f32_16x16x32_bf16(kf0, qf0, s_acc[nb], 0, 0, 0);
                s_acc[nb] = __builtin_amdgcn_mfma_f32_16x16x32_bf16(kf1, qf1, s_acc[nb], 0, 0, 0);
            }
            __builtin_amdgcn_s_setprio(0);

            const bool diag = (jt == qtile);
            float p[4][4];
            float mx = -1e30f;
#pragma unroll
            for (int nb = 0; nb < 4; ++nb) {
#pragma unroll
                for (int r = 0; r < 4; ++r) {
                    float s = s_acc[nb][r];
                    if (diag) {
                        const int key = j0 + ((nb & 2) << 4) + (quad << 3) + ((nb & 1) << 2) + r;
                        if (key > qg) s = -1e30f;
                    }
                    p[nb][r] = s;
                    mx = fmaxf(mx, s);
                }
            }
            mx = fmaxf(mx, __shfl_xor(mx, 16, 64));
            mx = fmaxf(mx, __shfl_xor(mx, 32, 64));

            // T13 defer-max: only rescale when some q-row's max grew by > 8
            if (!__all(mx <= m_q + 8.0f)) {
                const float mn = fmaxf(m_q, mx);
                const float alpha = __expf(m_q - mn);
                m_q = mn;
                l_r *= alpha;
#pragma unroll
                for (int nb = 0; nb < 4; ++nb) o_acc[nb] *= alpha;
            }

            float ts = 0.f;
#pragma unroll
            for (int nb = 0; nb < 4; ++nb)
#pragma unroll
                for (int r = 0; r < 4; ++r) {
                    const float e = __expf(p[nb][r] - m_q);
                    p[nb][r] = e;
                    ts += e;
                }
            ts += __shfl_xor(ts, 16, 64);
            ts += __shfl_xor(ts, 32, 64);
            l_r += ts;

            bf16x8 pb0, pb1;
#pragma unroll
            for (int r = 0; r < 4; ++r) {
                pb0[r]     = (bf16)p[0][r];
                pb0[4 + r] = (bf16)p[1][r];
                pb1[r]     = (bf16)p[2][r];
                pb1[4 + r] = (bf16)p[3][r];
            }

            // O^T += V^T . P^T : A = V^T fragment, B = pb in regs
            __builtin_amdgcn_s_setprio(1);
#pragma unroll
            for (int nb = 0; nb < 4; ++nb) {
                const int row = nb * 16 + l16;
                const int slot = quad ^ xr;
                bf16x8 vf0 = *reinterpret_cast<const bf16x8*>(&sVc[row * 64 + slot * 8]);
                bf16x8 vf1 = *reinterpret_cast<const bf16x8*>(&sVc[row * 64 + (slot ^ 4) * 8]);
                o_acc[nb] = __builtin_amdgcn_mfma_f32_16x16x32_bf16(vf0, pb0, o_acc[nb], 0, 0, 0);
                o_acc[nb] = __builtin_amdgcn_mfma_f32_16x16x32_bf16(vf1, pb1, o_acc[nb], 0, 0, 0);
            }
            __builtin_amdgcn_s_setprio(0);
            __syncthreads();   // all waves done with cur; prefetch landed (vmcnt drain)
        }

        const float inv = 1.f / l_r;
#pragma unroll
        for (int nb = 0; nb < 4; ++nb) {
            bf16x4 ov;
#pragma unroll
            for (int r = 0; r < 4; ++r) ov[r] = (bf16)(o_acc[nb][r] * inv);
            *reinterpret_cast<bf16x4*>(
                &o[(size_t)(b * SEQ + qg) * D_MODEL + h * D_HEAD + nb * 16 + quad * 4]) = ov;
        }
    }
}

// ---------------- launch ----------------
// fp32 I/O. resid lives in d_out. Workspace (lifetime-aliased):
//   [0,24)   MB : bf16 weights wq|wk|wv (=wqkv) |wo|fc1|fc2
//   [24,40)  MB : n1 -> attn -> hid(start)
//   [40,72)  MB : qk [8192,2048] (dead after flash)
//   [72,88)  MB : vT (dead after flash)
//   MLP: if ws >= 104 MB: hid = [24,88), n2 = [88,104); else 2-chunk, n2 = [72,88).
extern "C" void kernel_launch(void* const* d_in, const int* in_sizes, int n_in,
                              void* d_out, int out_size, void* d_ws, size_t ws_size,
                              hipStream_t stream) {
    const float* x      = (const float*)d_in[0];
    const float* gamma1 = (const float*)d_in[1];
    const float* beta1  = (const float*)d_in[2];
    const float* wq     = (const float*)d_in[3];
    const float* wk     = (const float*)d_in[4];
    const float* wv     = (const float*)d_in[5];
    const float* wo     = (const float*)d_in[6];
    const float* gamma2 = (const float*)d_in[7];
    const float* beta2  = (const float*)d_in[8];
    const float* fc1    = (const float*)d_in[9];
    const float* fc2    = (const float*)d_in[10];
    float* out = (float*)d_out;

    const size_t WSMALL = (size_t)N_HEADS * D_HEAD * D_MODEL;  // 1,048,576
    const size_t WFF    = (size_t)D_FF * D_MODEL;              // 4,194,304
    const size_t RD     = (size_t)ROWS * D_MODEL;              // 8,388,608

    char* wsb = (char*)d_ws;
    bf16* wq_b  = (bf16*)(wsb);           // wq|wk|wv contiguous = wqkv [3072,1024]
    bf16* wk_b  = wq_b + WSMALL;
    bf16* wv_b  = wk_b + WSMALL;
    bf16* wo_b  = wv_b + WSMALL;
    bf16* fc1_b = wo_b + WSMALL;
    bf16* fc2_b = fc1_b + WFF;            // ends at 24 MB
    bf16* slotA = fc2_b + WFF;            // [24,40): n1 -> attn -> hid
    bf16* qkb   = slotA + RD;             // [40,72): q|k stride-2048
    bf16* vtb   = qkb + 2 * RD;           // [72,88)

    bf16* n1    = slotA;
    bf16* attnb = slotA;
    bf16* hid   = slotA;
    float* resid = out;

    const size_t need_single = (size_t)(24 + 64 + 16) * 1024 * 1024;
    const bool single = ws_size >= need_single;
    bf16* n2 = single ? (bf16*)(wsb + (size_t)88 * 1024 * 1024) : vtb;

    // prep: all six weight converts + LN1 in one dispatch (R14)
    prep_kernel<<<CONVB + ROWS, 256, 0, stream>>>(wq, wk, wv, wo, fc1, fc2, wq_b,
                                                  x, gamma1, beta1, n1);
    // fused QKV: BK=64 swizzled + tbuf union (R4); ORD=1 (frozen bundle)
    gemm_mt<4, 128, 64, 1, bf16><<<(3072 / 128) * (ROWS / 128), 256, 0, stream>>>(n1, wq_b, qkb, nullptr, vtb, ROWS, 3072, D_MODEL, D_MODEL);
    // flash attention (R5 structure + R10 setprio/defer-max + R15 1-qtile/block)
    flash_attn_kernel<<<2048, 256, 0, stream>>>(qkb, vtb, attnb);
    // resid(d_out) = x + attn @ wo^T — TN=64/ORD=0, m97 structure
    gemm_mt<2, 64, 64, 0, float><<<(D_MODEL / 64) * (ROWS / 128), 256, 0, stream>>>(attnb, wo_b, resid, x, nullptr, ROWS, D_MODEL, D_MODEL, D_MODEL);
    // LN2
    ln_kernel<<<ROWS, 256, 0, stream>>>(resid, gamma2, beta2, n2);

    if (single) {
        // FC1: TN=128/BK=64/ORD=1 (frozen bundle), m97 structure
        gemm_mt<1, 128, 64, 1, bf16><<<(D_FF / 128) * (ROWS / 128), 256, 0, stream>>>(n2, fc1_b, hid, nullptr, nullptr, ROWS, D_FF, D_MODEL, D_MODEL);
        // FC2: TN=64/ORD=0, m97 structure
        gemm_mt<2, 64, 64, 0, float><<<(D_MODEL / 64) * (ROWS / 128), 256, 0, stream>>>(hid, fc2_b, out, resid, nullptr, ROWS, D_MODEL, D_FF, D_FF);
    } else {
        const int CHUNK = 4096;   // hid chunk = 32 MB in [24,56); CHUNK/128 = 32 (div by 8 ok)
        for (int c = 0; c < ROWS / CHUNK; ++c) {
            const bf16*  n2c    = n2    + (size_t)c * CHUNK * D_MODEL;
            const float* residc = resid + (size_t)c * CHUNK * D_MODEL;
            float*       outc   = out   + (size_t)c * CHUNK * D_MODEL;
            gemm_mt<1, 128, 64, 1, bf16><<<(D_FF / 128) * (CHUNK / 128), 256, 0, stream>>>(n2c, fc1_b, hid, nullptr, nullptr, CHUNK, D_FF, D_MODEL, D_MODEL);
            gemm_mt<2, 64, 64, 0, float><<<(D_MODEL / 64) * (CHUNK / 128), 256, 0, stream>>>(hid, fc2_b, outc, residc, nullptr, CHUNK, D_MODEL, D_FF, D_FF);
        }
    }
}